// Round 2
// baseline (2754.008 us; speedup 1.0000x reference)
//
#include <hip/hip_runtime.h>
#include <math.h>

#define B_ 4
#define T_ 1024
#define D_ 1024
#define H_ 16
#define DH_ 64
#define NCAT 2112   // 1024 (Q) + 1024 (K) + 64 (V)

// ---------------------------------------------------------------------------
// Concatenate Wq|Wk|Wv -> Wcat [1024][2112], biases -> bcat [2112]
// ---------------------------------------------------------------------------
__global__ __launch_bounds__(256) void concat_w(
    const float* __restrict__ Wq, const float* __restrict__ Wk,
    const float* __restrict__ Wv, const float* __restrict__ bq,
    const float* __restrict__ bk, const float* __restrict__ bv,
    float* __restrict__ Wcat, float* __restrict__ bcat) {
  int idx = blockIdx.x * 256 + threadIdx.x;
  const int total = 1024 * NCAT;
  for (int i = idx; i < total; i += gridDim.x * 256) {
    int k = i / NCAT, n = i % NCAT;
    float v;
    if (n < 1024)       v = Wq[k * 1024 + n];
    else if (n < 2048)  v = Wk[k * 1024 + (n - 1024)];
    else                v = Wv[k * 64 + (n - 2048)];
    Wcat[i] = v;
  }
  if (idx < NCAT) {
    float v;
    if (idx < 1024)      v = bq[idx];
    else if (idx < 2048) v = bk[idx - 1024];
    else                 v = bv[idx - 2048];
    bcat[idx] = v;
  }
}

// ---------------------------------------------------------------------------
// fp32 GEMM + bias: C[M][N](ldc) = A[M][K](lda=K) @ B[K][N](ldb) + bias[N]
// 128x128 block tile, BK=16, 256 threads, 8x8 per thread.
// M % 128 == 0 and K % 16 == 0 assumed (true for all our shapes).
// ---------------------------------------------------------------------------
__global__ __launch_bounds__(256) void gemm_bias(
    const float* __restrict__ A, const float* __restrict__ Bm,
    const float* __restrict__ bias, float* __restrict__ C,
    int M, int N, int K, int ldb, int ldc) {
  __shared__ float As[16][132];  // [k][m] (transposed store)
  __shared__ float Bs[16][132];  // [k][n]
  const int tid = threadIdx.x;
  const int tx = tid & 15, ty = tid >> 4;
  const int m0 = blockIdx.x * 128, n0 = blockIdx.y * 128;
  float acc[8][8] = {};
  for (int k0 = 0; k0 < K; k0 += 16) {
#pragma unroll
    for (int s = 0; s < 8; s++) {  // A tile: 128x16
      int i = tid + 256 * s;
      int r = i >> 4, c = i & 15;
      As[c][r] = A[(size_t)(m0 + r) * K + k0 + c];
    }
#pragma unroll
    for (int s = 0; s < 8; s++) {  // B tile: 16x128
      int i = tid + 256 * s;
      int r = i >> 7, c = i & 127;
      int n = n0 + c;
      Bs[r][c] = (n < N) ? Bm[(size_t)(k0 + r) * ldb + n] : 0.f;
    }
    __syncthreads();
#pragma unroll
    for (int kk = 0; kk < 16; kk++) {
      float a[8], b[8];
#pragma unroll
      for (int i = 0; i < 8; i++) a[i] = As[kk][ty * 8 + i];
#pragma unroll
      for (int j = 0; j < 8; j++) b[j] = Bs[kk][tx * 8 + j];
#pragma unroll
      for (int i = 0; i < 8; i++)
#pragma unroll
        for (int j = 0; j < 8; j++)
          acc[i][j] = fmaf(a[i], b[j], acc[i][j]);
    }
    __syncthreads();
  }
#pragma unroll
  for (int i = 0; i < 8; i++) {
    int m = m0 + ty * 8 + i;
#pragma unroll
    for (int j = 0; j < 8; j++) {
      int n = n0 + tx * 8 + j;
      if (n < N) C[(size_t)m * ldc + n] = acc[i][j] + bias[n];
    }
  }
}

// ---------------------------------------------------------------------------
// Softmax row stats: m = rowmax(scores), linv = 1/sum(exp(s-m))
// grid: B*H*(T/16) blocks, 256 threads. Q at col 0, K at col 1024 of Cqkv.
// ---------------------------------------------------------------------------
__global__ __launch_bounds__(256) void attn_stats(
    const float* __restrict__ Cqkv, float* __restrict__ mrow,
    float* __restrict__ linv) {
  __shared__ float Qs[16][68];
  __shared__ float Ks[64][68];
  const int bi = blockIdx.x;
  const int qt = bi & 63, h = (bi >> 6) & 15, b = bi >> 10;
  const int tid = threadIdx.x;
  const int q0 = qt * 16;
  const float scale = 0.125f;  // DH^-0.5
  {
    int r = tid >> 4, c4 = tid & 15;
    *(float4*)&Qs[r][c4 * 4] =
        *(const float4*)&Cqkv[(size_t)(b * T_ + q0 + r) * NCAT + h * DH_ + c4 * 4];
  }
  __syncthreads();
  const int q = tid >> 4, kg = tid & 15;
  float Qr[64];
#pragma unroll
  for (int d4 = 0; d4 < 16; d4++) {
    float4 v = *(float4*)&Qs[q][d4 * 4];
    Qr[d4 * 4 + 0] = v.x; Qr[d4 * 4 + 1] = v.y;
    Qr[d4 * 4 + 2] = v.z; Qr[d4 * 4 + 3] = v.w;
  }
  float m_loc = -1e30f, l_loc = 0.f;
  for (int kt = 0; kt < 16; kt++) {
#pragma unroll
    for (int s = 0; s < 4; s++) {
      int i = tid + 256 * s;
      int r = i >> 4, c4 = i & 15;
      *(float4*)&Ks[r][c4 * 4] =
          *(const float4*)&Cqkv[(size_t)(b * T_ + kt * 64 + r) * NCAT + 1024 + h * DH_ + c4 * 4];
    }
    __syncthreads();
#pragma unroll
    for (int jj = 0; jj < 4; jj++) {
      int kk = kg + 16 * jj;
      float s = 0.f;
#pragma unroll
      for (int d4 = 0; d4 < 16; d4++) {
        float4 v = *(float4*)&Ks[kk][d4 * 4];
        s = fmaf(Qr[d4 * 4 + 0], v.x, s);
        s = fmaf(Qr[d4 * 4 + 1], v.y, s);
        s = fmaf(Qr[d4 * 4 + 2], v.z, s);
        s = fmaf(Qr[d4 * 4 + 3], v.w, s);
      }
      s *= scale;
      float mn = fmaxf(m_loc, s);
      l_loc = l_loc * __expf(m_loc - mn) + __expf(s - mn);
      m_loc = mn;
    }
    __syncthreads();
  }
  // reduce (m,l) across the 16 lanes sharing q
#pragma unroll
  for (int off = 1; off < 16; off <<= 1) {
    float om = __shfl_xor(m_loc, off, 16);
    float ol = __shfl_xor(l_loc, off, 16);
    float mn = fmaxf(m_loc, om);
    l_loc = l_loc * __expf(m_loc - mn) + ol * __expf(om - mn);
    m_loc = mn;
  }
  if (kg == 0) {
    int idx = (b * H_ + h) * T_ + q0 + q;
    mrow[idx] = m_loc;
    linv[idx] = 1.0f / l_loc;
  }
}

// ---------------------------------------------------------------------------
// attn_mean[b][q][k] = (1/H) * sum_h softmax(scores)[b][h][q][k]
// grid: B*(T/16) blocks, 256 threads. kt outer, h inner, register accumulate.
// ---------------------------------------------------------------------------
__global__ __launch_bounds__(256) void attn_mean_k(
    const float* __restrict__ Cqkv, const float* __restrict__ mrow,
    const float* __restrict__ linv, float* __restrict__ am_out) {
  __shared__ float Qs[16][68];
  __shared__ float Ks[64][68];
  const int bi = blockIdx.x;
  const int qt = bi & 63, b = bi >> 6;
  const int q0 = qt * 16, tid = threadIdx.x;
  const int q = tid >> 4, kg = tid & 15;
  const float scale = 0.125f;
  for (int kt = 0; kt < 16; kt++) {
    float am4[4] = {0.f, 0.f, 0.f, 0.f};
    for (int h = 0; h < H_; h++) {
      {
        int r = tid >> 4, c4 = tid & 15;
        *(float4*)&Qs[r][c4 * 4] =
            *(const float4*)&Cqkv[(size_t)(b * T_ + q0 + r) * NCAT + h * DH_ + c4 * 4];
      }
#pragma unroll
      for (int s = 0; s < 4; s++) {
        int i = tid + 256 * s;
        int r = i >> 4, c4 = i & 15;
        *(float4*)&Ks[r][c4 * 4] =
            *(const float4*)&Cqkv[(size_t)(b * T_ + kt * 64 + r) * NCAT + 1024 + h * DH_ + c4 * 4];
      }
      __syncthreads();
      float mq = mrow[(b * H_ + h) * T_ + q0 + q];
      float li = linv[(b * H_ + h) * T_ + q0 + q];
      float Qr[64];
#pragma unroll
      for (int d4 = 0; d4 < 16; d4++) {
        float4 v = *(float4*)&Qs[q][d4 * 4];
        Qr[d4 * 4 + 0] = v.x; Qr[d4 * 4 + 1] = v.y;
        Qr[d4 * 4 + 2] = v.z; Qr[d4 * 4 + 3] = v.w;
      }
#pragma unroll
      for (int jj = 0; jj < 4; jj++) {
        int kk = kg + 16 * jj;
        float s = 0.f;
#pragma unroll
        for (int d4 = 0; d4 < 16; d4++) {
          float4 v = *(float4*)&Ks[kk][d4 * 4];
          s = fmaf(Qr[d4 * 4 + 0], v.x, s);
          s = fmaf(Qr[d4 * 4 + 1], v.y, s);
          s = fmaf(Qr[d4 * 4 + 2], v.z, s);
          s = fmaf(Qr[d4 * 4 + 3], v.w, s);
        }
        am4[jj] += __expf(s * scale - mq) * li;
      }
      __syncthreads();
    }
#pragma unroll
    for (int jj = 0; jj < 4; jj++) {
      int k = kt * 64 + kg + 16 * jj;
      am_out[((size_t)b * T_ + q0 + q) * T_ + k] = am4[jj] * (1.0f / 16.0f);
    }
  }
}

// ---------------------------------------------------------------------------
// out_pre[b][q][h*64+d] = sum_k P[b][h][q][k] * V[b][k][d]
// grid: B*(T/16) blocks, 256 threads. h outer, kt inner, P via LDS.
// ---------------------------------------------------------------------------
__global__ __launch_bounds__(256) void attn_out_k(
    const float* __restrict__ Cqkv, const float* __restrict__ mrow,
    const float* __restrict__ linv, float* __restrict__ out_pre) {
  __shared__ float Qs[16][68];
  __shared__ float Ks[64][68];
  __shared__ float Vs[64][68];
  __shared__ float Ps[16][68];
  const int bi = blockIdx.x;
  const int qt = bi & 63, b = bi >> 6;
  const int q0 = qt * 16, tid = threadIdx.x;
  const int q = tid >> 4, x16 = tid & 15;  // kg in S phase, dg in PV phase
  const float scale = 0.125f;
  for (int h = 0; h < H_; h++) {
    {
      int r = tid >> 4, c4 = tid & 15;
      *(float4*)&Qs[r][c4 * 4] =
          *(const float4*)&Cqkv[(size_t)(b * T_ + q0 + r) * NCAT + h * DH_ + c4 * 4];
    }
    __syncthreads();
    float Qr[64];
#pragma unroll
    for (int d4 = 0; d4 < 16; d4++) {
      float4 v = *(float4*)&Qs[q][d4 * 4];
      Qr[d4 * 4 + 0] = v.x; Qr[d4 * 4 + 1] = v.y;
      Qr[d4 * 4 + 2] = v.z; Qr[d4 * 4 + 3] = v.w;
    }
    const float mq = mrow[(b * H_ + h) * T_ + q0 + q];
    const float li = linv[(b * H_ + h) * T_ + q0 + q];
    float po[4] = {0.f, 0.f, 0.f, 0.f};
    for (int kt = 0; kt < 16; kt++) {
#pragma unroll
      for (int s = 0; s < 4; s++) {
        int i = tid + 256 * s;
        int r = i >> 4, c4 = i & 15;
        *(float4*)&Ks[r][c4 * 4] =
            *(const float4*)&Cqkv[(size_t)(b * T_ + kt * 64 + r) * NCAT + 1024 + h * DH_ + c4 * 4];
        *(float4*)&Vs[r][c4 * 4] =
            *(const float4*)&Cqkv[(size_t)(b * T_ + kt * 64 + r) * NCAT + 2048 + c4 * 4];
      }
      __syncthreads();
      // S phase: thread (q, kg=x16) does 4 rows
#pragma unroll
      for (int jj = 0; jj < 4; jj++) {
        int kk = x16 + 16 * jj;
        float s = 0.f;
#pragma unroll
        for (int d4 = 0; d4 < 16; d4++) {
          float4 v = *(float4*)&Ks[kk][d4 * 4];
          s = fmaf(Qr[d4 * 4 + 0], v.x, s);
          s = fmaf(Qr[d4 * 4 + 1], v.y, s);
          s = fmaf(Qr[d4 * 4 + 2], v.z, s);
          s = fmaf(Qr[d4 * 4 + 3], v.w, s);
        }
        Ps[q][kk] = __expf(s * scale - mq) * li;
      }
      __syncthreads();
      // PV phase: thread (q, dg=x16) accumulates 4 output dims
#pragma unroll
      for (int kk = 0; kk < 64; kk++) {
        float p = Ps[q][kk];
        float4 v = *(float4*)&Vs[kk][x16 * 4];
        po[0] = fmaf(p, v.x, po[0]);
        po[1] = fmaf(p, v.y, po[1]);
        po[2] = fmaf(p, v.z, po[2]);
        po[3] = fmaf(p, v.w, po[3]);
      }
      __syncthreads();
    }
    int col = h * DH_ + x16 * 4;
    float4 o; o.x = po[0]; o.y = po[1]; o.z = po[2]; o.w = po[3];
    *(float4*)&out_pre[((size_t)b * T_ + q0 + q) * D_ + col] = o;
  }
}

// ---------------------------------------------------------------------------
extern "C" void kernel_launch(void* const* d_in, const int* in_sizes, int n_in,
                              void* d_out, int out_size, void* d_ws, size_t ws_size,
                              hipStream_t stream) {
  const float* x  = (const float*)d_in[0];
  const float* Wq = (const float*)d_in[1];
  const float* bq = (const float*)d_in[2];
  const float* Wk = (const float*)d_in[3];
  const float* bk = (const float*)d_in[4];
  const float* Wv = (const float*)d_in[5];
  const float* bv = (const float*)d_in[6];
  const float* Wo = (const float*)d_in[7];
  const float* bo = (const float*)d_in[8];

  float* out = (float*)d_out;                      // [B,T,D]
  float* am  = out + (size_t)B_ * T_ * D_;         // [B,T,T]

  float* ws      = (float*)d_ws;
  float* Wcat    = ws;                              // 1024*2112
  float* bcat    = Wcat + (size_t)1024 * NCAT;      // 2112
  float* Cqkv    = bcat + NCAT;                     // 4096*2112
  float* mrow    = Cqkv + (size_t)4096 * NCAT;      // 65536
  float* linvp   = mrow + (size_t)B_ * H_ * T_;     // 65536
  float* out_pre = linvp + (size_t)B_ * H_ * T_;    // 4096*1024

  concat_w<<<512, 256, 0, stream>>>(Wq, Wk, Wv, bq, bk, bv, Wcat, bcat);
  gemm_bias<<<dim3(32, 17), 256, 0, stream>>>(x, Wcat, bcat, Cqkv,
                                              B_ * T_, NCAT, D_, NCAT, NCAT);
  attn_stats<<<B_ * H_ * (T_ / 16), 256, 0, stream>>>(Cqkv, mrow, linvp);
  attn_mean_k<<<B_ * (T_ / 16), 256, 0, stream>>>(Cqkv, mrow, linvp, am);
  attn_out_k<<<B_ * (T_ / 16), 256, 0, stream>>>(Cqkv, mrow, linvp, out_pre);
  gemm_bias<<<dim3(32, 8), 256, 0, stream>>>(out_pre, Wo, bo, out,
                                             B_ * T_, D_, D_, D_, D_);
}

// Round 3
// 1396.457 us; speedup vs baseline: 1.9721x; 1.9721x over previous
//
#include <hip/hip_runtime.h>
#include <math.h>

#define B_ 4
#define T_ 1024
#define D_ 1024
#define H_ 16
#define DH_ 64
#define NCAT 2112   // 1024 (Q) + 1024 (K) + 64 (V)

// ---------------------------------------------------------------------------
// Concatenate Wq|Wk|Wv -> Wcat [1024][2112], biases -> bcat [2112]
// ---------------------------------------------------------------------------
__global__ __launch_bounds__(256) void concat_w(
    const float* __restrict__ Wq, const float* __restrict__ Wk,
    const float* __restrict__ Wv, const float* __restrict__ bq,
    const float* __restrict__ bk, const float* __restrict__ bv,
    float* __restrict__ Wcat, float* __restrict__ bcat) {
  int idx = blockIdx.x * 256 + threadIdx.x;
  const int total = 1024 * NCAT;
  for (int i = idx; i < total; i += gridDim.x * 256) {
    int k = i / NCAT, n = i % NCAT;
    float v;
    if (n < 1024)       v = Wq[k * 1024 + n];
    else if (n < 2048)  v = Wk[k * 1024 + (n - 1024)];
    else                v = Wv[k * 64 + (n - 2048)];
    Wcat[i] = v;
  }
  if (idx < NCAT) {
    float v;
    if (idx < 1024)      v = bq[idx];
    else if (idx < 2048) v = bk[idx - 1024];
    else                 v = bv[idx - 2048];
    bcat[idx] = v;
  }
}

// ---------------------------------------------------------------------------
// fp32 GEMM + bias: C[M][N](ldc) = A[M][K](lda=K) @ B[K][N](ldb) + bias[N]
// 128x128 block tile, BK=16, 256 threads, 8x8 per thread.
// ---------------------------------------------------------------------------
__global__ __launch_bounds__(256) void gemm_bias(
    const float* __restrict__ A, const float* __restrict__ Bm,
    const float* __restrict__ bias, float* __restrict__ C,
    int M, int N, int K, int ldb, int ldc) {
  __shared__ float As[16][132];  // [k][m] (transposed store)
  __shared__ float Bs[16][132];  // [k][n]
  const int tid = threadIdx.x;
  const int tx = tid & 15, ty = tid >> 4;
  const int m0 = blockIdx.x * 128, n0 = blockIdx.y * 128;
  float acc[8][8] = {};
  for (int k0 = 0; k0 < K; k0 += 16) {
#pragma unroll
    for (int s = 0; s < 8; s++) {  // A tile: 128x16
      int i = tid + 256 * s;
      int r = i >> 4, c = i & 15;
      As[c][r] = A[(size_t)(m0 + r) * K + k0 + c];
    }
#pragma unroll
    for (int s = 0; s < 8; s++) {  // B tile: 16x128
      int i = tid + 256 * s;
      int r = i >> 7, c = i & 127;
      int n = n0 + c;
      Bs[r][c] = (n < N) ? Bm[(size_t)(k0 + r) * ldb + n] : 0.f;
    }
    __syncthreads();
#pragma unroll
    for (int kk = 0; kk < 16; kk++) {
      float a[8], b[8];
#pragma unroll
      for (int i = 0; i < 8; i++) a[i] = As[kk][ty * 8 + i];
#pragma unroll
      for (int j = 0; j < 8; j++) b[j] = Bs[kk][tx * 8 + j];
#pragma unroll
      for (int i = 0; i < 8; i++)
#pragma unroll
        for (int j = 0; j < 8; j++)
          acc[i][j] = fmaf(a[i], b[j], acc[i][j]);
    }
    __syncthreads();
  }
#pragma unroll
  for (int i = 0; i < 8; i++) {
    int m = m0 + ty * 8 + i;
#pragma unroll
    for (int j = 0; j < 8; j++) {
      int n = n0 + tx * 8 + j;
      if (n < N) C[(size_t)m * ldc + n] = acc[i][j] + bias[n];
    }
  }
}

// ---------------------------------------------------------------------------
// Fused flash attention per head: grid = B*H*(T/16) = 4096 blocks.
// Block (b,h,qt): 16 q rows, online softmax over 16 k-tiles of 64.
// Writes out_pre[b][q][h*64+d], plus mrow/linv for the attn_mean pass.
// ---------------------------------------------------------------------------
__global__ __launch_bounds__(256) void attn_fused(
    const float* __restrict__ Cqkv, float* __restrict__ mrow,
    float* __restrict__ linv, float* __restrict__ out_pre) {
  __shared__ float Ks[64][68];
  __shared__ float Vs[64][68];
  __shared__ float Ps[16][68];
  const int bi = blockIdx.x;
  const int qt = bi & 63, h = (bi >> 6) & 15, b = bi >> 10;
  const int q0 = qt * 16, tid = threadIdx.x;
  const int q = tid >> 4, x16 = tid & 15;  // kg in S phase, dg in PV phase
  const float scale = 0.125f;
  // Q row (cols h*64..h*64+63) straight from global (L2-resident)
  float Qr[64];
  const float* qrow = &Cqkv[(size_t)(b * T_ + q0 + q) * NCAT + h * DH_];
#pragma unroll
  for (int d4 = 0; d4 < 16; d4++) {
    float4 v = *(const float4*)&qrow[d4 * 4];
    Qr[d4 * 4 + 0] = v.x; Qr[d4 * 4 + 1] = v.y;
    Qr[d4 * 4 + 2] = v.z; Qr[d4 * 4 + 3] = v.w;
  }
  float m_run = -1e30f, l_run = 0.f;
  float po[4] = {0.f, 0.f, 0.f, 0.f};
  for (int kt = 0; kt < 16; kt++) {
#pragma unroll
    for (int s = 0; s < 4; s++) {
      int i = tid + 256 * s;
      int r = i >> 4, c4 = i & 15;
      const float* krow = &Cqkv[(size_t)(b * T_ + kt * 64 + r) * NCAT];
      *(float4*)&Ks[r][c4 * 4] = *(const float4*)&krow[1024 + h * DH_ + c4 * 4];
      *(float4*)&Vs[r][c4 * 4] = *(const float4*)&krow[2048 + c4 * 4];
    }
    __syncthreads();
    // S phase: thread (q, kg=x16) computes 4 scores
    float p[4];
    float tm = -1e30f;
#pragma unroll
    for (int jj = 0; jj < 4; jj++) {
      int kk = x16 + 16 * jj;
      float s = 0.f;
#pragma unroll
      for (int d4 = 0; d4 < 16; d4++) {
        float4 v = *(float4*)&Ks[kk][d4 * 4];
        s = fmaf(Qr[d4 * 4 + 0], v.x, s);
        s = fmaf(Qr[d4 * 4 + 1], v.y, s);
        s = fmaf(Qr[d4 * 4 + 2], v.z, s);
        s = fmaf(Qr[d4 * 4 + 3], v.w, s);
      }
      p[jj] = s * scale;
      tm = fmaxf(tm, p[jj]);
    }
    // tile row-max across the 16 lanes sharing q (butterfly -> all lanes)
#pragma unroll
    for (int off = 1; off < 16; off <<= 1)
      tm = fmaxf(tm, __shfl_xor(tm, off, 16));
    float m_new = fmaxf(m_run, tm);
    float c = __expf(m_run - m_new);
    float ts = 0.f;
#pragma unroll
    for (int jj = 0; jj < 4; jj++) {
      p[jj] = __expf(p[jj] - m_new);
      ts += p[jj];
      Ps[q][x16 + 16 * jj] = p[jj];
    }
#pragma unroll
    for (int off = 1; off < 16; off <<= 1)
      ts += __shfl_xor(ts, off, 16);
    l_run = l_run * c + ts;
    m_run = m_new;
    __syncthreads();
    // PV phase: thread (q, dg=x16) accumulates 4 output dims, rescaled
#pragma unroll
    for (int jj = 0; jj < 4; jj++) po[jj] *= c;
#pragma unroll
    for (int kk = 0; kk < 64; kk++) {
      float pp = Ps[q][kk];
      float4 v = *(float4*)&Vs[kk][x16 * 4];
      po[0] = fmaf(pp, v.x, po[0]);
      po[1] = fmaf(pp, v.y, po[1]);
      po[2] = fmaf(pp, v.z, po[2]);
      po[3] = fmaf(pp, v.w, po[3]);
    }
    __syncthreads();
  }
  const float li = 1.0f / l_run;
  if (x16 == 0) {
    int idx = (b * H_ + h) * T_ + q0 + q;
    mrow[idx] = m_run;
    linv[idx] = li;
  }
  int col = h * DH_ + x16 * 4;
  float4 o;
  o.x = po[0] * li; o.y = po[1] * li; o.z = po[2] * li; o.w = po[3] * li;
  *(float4*)&out_pre[((size_t)b * T_ + q0 + q) * D_ + col] = o;
}

// ---------------------------------------------------------------------------
// attn_mean[b][q][k] = (1/H) * sum_h P[b][h][q][k]
// grid = B*(T/16)*(T/64) = 4096 blocks; block (b,qt,kc) owns a 16x64 slice,
// loops h internally using saved mrow/linv. No atomics.
// ---------------------------------------------------------------------------
__global__ __launch_bounds__(256) void attn_mean_k(
    const float* __restrict__ Cqkv, const float* __restrict__ mrow,
    const float* __restrict__ linv, float* __restrict__ am_out) {
  __shared__ float Ks[64][68];
  const int bi = blockIdx.x;
  const int kc = bi & 15, qt = (bi >> 4) & 63, b = bi >> 10;
  const int q0 = qt * 16, k0 = kc * 64, tid = threadIdx.x;
  const int q = tid >> 4, kg = tid & 15;
  const float scale = 0.125f;
  float am4[4] = {0.f, 0.f, 0.f, 0.f};
  for (int h = 0; h < H_; h++) {
#pragma unroll
    for (int s = 0; s < 4; s++) {
      int i = tid + 256 * s;
      int r = i >> 4, c4 = i & 15;
      *(float4*)&Ks[r][c4 * 4] =
          *(const float4*)&Cqkv[(size_t)(b * T_ + k0 + r) * NCAT + 1024 + h * DH_ + c4 * 4];
    }
    __syncthreads();
    const float mq = mrow[(b * H_ + h) * T_ + q0 + q];
    const float li = linv[(b * H_ + h) * T_ + q0 + q];
    const float* qrow = &Cqkv[(size_t)(b * T_ + q0 + q) * NCAT + h * DH_];
    float Qr[64];
#pragma unroll
    for (int d4 = 0; d4 < 16; d4++) {
      float4 v = *(const float4*)&qrow[d4 * 4];
      Qr[d4 * 4 + 0] = v.x; Qr[d4 * 4 + 1] = v.y;
      Qr[d4 * 4 + 2] = v.z; Qr[d4 * 4 + 3] = v.w;
    }
#pragma unroll
    for (int jj = 0; jj < 4; jj++) {
      int kk = kg + 16 * jj;
      float s = 0.f;
#pragma unroll
      for (int d4 = 0; d4 < 16; d4++) {
        float4 v = *(float4*)&Ks[kk][d4 * 4];
        s = fmaf(Qr[d4 * 4 + 0], v.x, s);
        s = fmaf(Qr[d4 * 4 + 1], v.y, s);
        s = fmaf(Qr[d4 * 4 + 2], v.z, s);
        s = fmaf(Qr[d4 * 4 + 3], v.w, s);
      }
      am4[jj] += __expf(s * scale - mq) * li;
    }
    __syncthreads();
  }
#pragma unroll
  for (int jj = 0; jj < 4; jj++) {
    int k = k0 + kg + 16 * jj;
    am_out[((size_t)b * T_ + q0 + q) * T_ + k] = am4[jj] * (1.0f / 16.0f);
  }
}

// ---------------------------------------------------------------------------
extern "C" void kernel_launch(void* const* d_in, const int* in_sizes, int n_in,
                              void* d_out, int out_size, void* d_ws, size_t ws_size,
                              hipStream_t stream) {
  const float* x  = (const float*)d_in[0];
  const float* Wq = (const float*)d_in[1];
  const float* bq = (const float*)d_in[2];
  const float* Wk = (const float*)d_in[3];
  const float* bk = (const float*)d_in[4];
  const float* Wv = (const float*)d_in[5];
  const float* bv = (const float*)d_in[6];
  const float* Wo = (const float*)d_in[7];
  const float* bo = (const float*)d_in[8];

  float* out = (float*)d_out;                      // [B,T,D]
  float* am  = out + (size_t)B_ * T_ * D_;         // [B,T,T]

  float* ws      = (float*)d_ws;
  float* Wcat    = ws;                              // 1024*2112
  float* bcat    = Wcat + (size_t)1024 * NCAT;      // 2112
  float* Cqkv    = bcat + NCAT;                     // 4096*2112
  float* mrow    = Cqkv + (size_t)4096 * NCAT;      // 65536
  float* linvp   = mrow + (size_t)B_ * H_ * T_;     // 65536
  float* out_pre = linvp + (size_t)B_ * H_ * T_;    // 4096*1024

  concat_w<<<512, 256, 0, stream>>>(Wq, Wk, Wv, bq, bk, bv, Wcat, bcat);
  gemm_bias<<<dim3(32, 17), 256, 0, stream>>>(x, Wcat, bcat, Cqkv,
                                              B_ * T_, NCAT, D_, NCAT, NCAT);
  attn_fused<<<B_ * H_ * (T_ / 16), 256, 0, stream>>>(Cqkv, mrow, linvp, out_pre);
  attn_mean_k<<<B_ * (T_ / 16) * (T_ / 64), 256, 0, stream>>>(Cqkv, mrow, linvp, am);
  gemm_bias<<<dim3(32, 8), 256, 0, stream>>>(out_pre, Wo, bo, out,
                                             B_ * T_, D_, D_, D_, D_);
}

// Round 4
// 728.162 us; speedup vs baseline: 3.7821x; 1.9178x over previous
//
#include <hip/hip_runtime.h>
#include <math.h>

#define B_ 4
#define T_ 1024
#define D_ 1024
#define H_ 16
#define DH_ 64
#define NCAT 2112   // 1024 (Q) + 1024 (K) + 64 (V)

typedef unsigned short u16;
typedef unsigned int u32;
typedef __attribute__((ext_vector_type(8))) short bf16x8;
typedef __attribute__((ext_vector_type(4))) float f32x4;

__device__ __forceinline__ u16 bf16rne(float f) {
  u32 u = __float_as_uint(f);
  u32 r = (u + 0x7fffu + ((u >> 16) & 1u)) >> 16;
  return (u16)r;
}
__device__ __forceinline__ float bf16tof(u16 h) {
  return __uint_as_float((u32)h << 16);
}

// ---------------------------------------------------------------------------
// Transpose + split-convert: W fp32 [K=1024][Nw] -> Thi/Tlo bf16 [.. roff+n ..][1024]
// grid (Nw/64, 16), 256 threads, 64x64 tile via LDS.
// ---------------------------------------------------------------------------
__global__ __launch_bounds__(256) void tconv(
    const float* __restrict__ W, int Nw,
    u16* __restrict__ Thi, u16* __restrict__ Tlo, int roff) {
  __shared__ float Ws[64][65];
  const int t = threadIdx.x;
  const int n0 = blockIdx.x * 64, k0 = blockIdx.y * 64;
#pragma unroll
  for (int rr = 0; rr < 4; rr++) {
    int r = rr * 16 + (t >> 4);
    int c = (t & 15) * 4;
    float4 v = *(const float4*)&W[(size_t)(k0 + r) * Nw + n0 + c];
    Ws[r][c] = v.x; Ws[r][c + 1] = v.y; Ws[r][c + 2] = v.z; Ws[r][c + 3] = v.w;
  }
  __syncthreads();
  const int n = t >> 2, kc = t & 3;
  u32 uh[8], ul[8];
#pragma unroll
  for (int j2 = 0; j2 < 8; j2++) {
    u16 hh[2], ll[2];
#pragma unroll
    for (int e = 0; e < 2; e++) {
      float v = Ws[kc * 16 + j2 * 2 + e][n];
      u16 h = bf16rne(v);
      hh[e] = h;
      ll[e] = bf16rne(v - bf16tof(h));
    }
    uh[j2] = (u32)hh[0] | ((u32)hh[1] << 16);
    ul[j2] = (u32)ll[0] | ((u32)ll[1] << 16);
  }
  size_t base = (size_t)(roff + n0 + n) * 1024 + k0 + kc * 16;
  *(uint4*)&Thi[base]     = make_uint4(uh[0], uh[1], uh[2], uh[3]);
  *(uint4*)&Thi[base + 8] = make_uint4(uh[4], uh[5], uh[6], uh[7]);
  *(uint4*)&Tlo[base]     = make_uint4(ul[0], ul[1], ul[2], ul[3]);
  *(uint4*)&Tlo[base + 8] = make_uint4(ul[4], ul[5], ul[6], ul[7]);
}

// ---------------------------------------------------------------------------
// Row-major split-convert: in fp32 [4096*1024] -> hi/lo bf16, same layout.
// grid 2048 x 256, 8 elems/thread.
// ---------------------------------------------------------------------------
__global__ __launch_bounds__(256) void rowconv(
    const float* __restrict__ in, u16* __restrict__ hi, u16* __restrict__ lo) {
  size_t i = ((size_t)blockIdx.x * 256 + threadIdx.x) * 8;
  float4 v0 = *(const float4*)&in[i];
  float4 v1 = *(const float4*)&in[i + 4];
  float vv[8] = {v0.x, v0.y, v0.z, v0.w, v1.x, v1.y, v1.z, v1.w};
  u32 uh[4], ul[4];
#pragma unroll
  for (int j = 0; j < 4; j++) {
    u16 h0 = bf16rne(vv[2 * j]);
    u16 h1 = bf16rne(vv[2 * j + 1]);
    u16 l0 = bf16rne(vv[2 * j] - bf16tof(h0));
    u16 l1 = bf16rne(vv[2 * j + 1] - bf16tof(h1));
    uh[j] = (u32)h0 | ((u32)h1 << 16);
    ul[j] = (u32)l0 | ((u32)l1 << 16);
  }
  *(uint4*)&hi[i] = make_uint4(uh[0], uh[1], uh[2], uh[3]);
  *(uint4*)&lo[i] = make_uint4(ul[0], ul[1], ul[2], ul[3]);
}

__global__ __launch_bounds__(256) void bias_concat(
    const float* __restrict__ bq, const float* __restrict__ bk,
    const float* __restrict__ bv, float* __restrict__ bcat) {
  int i = blockIdx.x * 256 + threadIdx.x;
  if (i < NCAT)
    bcat[i] = (i < 1024) ? bq[i] : ((i < 2048) ? bk[i - 1024] : bv[i - 2048]);
}

// ---------------------------------------------------------------------------
// Split-bf16 MFMA GEMM + bias:
// C[M][Nvalid](ldc) = Ahi/lo[M][Kd] @ (Bhi/lo[N][Kd])^T + bias, via
// Ah@Bh + Ah@Bl + Al@Bh in one fp32 accumulator.
// 128x128 tile, BK=32, 256 threads = 4 waves (2x2), 64x64 per wave.
// mfma_f32_16x16x32_bf16: A/B frag: row/col=lane&15, k=8*(lane>>4)+j;
// C/D: col=lane&15, row=4*(lane>>4)+reg (verified layout).
// ---------------------------------------------------------------------------
__global__ __launch_bounds__(256) void mfma_gemm(
    const u16* __restrict__ Ahi, const u16* __restrict__ Alo,
    const u16* __restrict__ Bhi, const u16* __restrict__ Blo,
    const float* __restrict__ bias, float* __restrict__ C,
    int Nvalid, int Kd, int ldc) {
  __shared__ u16 Ah[128][40];  // +8 pad: 80B row stride -> 2-way bank (free)
  __shared__ u16 Al[128][40];
  __shared__ u16 Bh[128][40];
  __shared__ u16 Bl[128][40];
  const int tid = threadIdx.x;
  const int lane = tid & 63, wid = tid >> 6;
  const int wr = wid >> 1, wc = wid & 1;
  const int m0 = blockIdx.x * 128, n0 = blockIdx.y * 128;
  f32x4 acc[4][4];
#pragma unroll
  for (int i = 0; i < 4; i++)
#pragma unroll
    for (int j = 0; j < 4; j++) {
      acc[i][j][0] = 0.f; acc[i][j][1] = 0.f;
      acc[i][j][2] = 0.f; acc[i][j][3] = 0.f;
    }
  const int fo = 8 * (lane >> 4);  // k offset of this lane's fragment
  const int fr = lane & 15;

#pragma unroll 1
  for (int k0 = 0; k0 < Kd; k0 += 32) {
    // stage 4 tiles of 128x32 bf16 (8KB each): 2 x 16B chunks per thread/array
#pragma unroll
    for (int s = 0; s < 2; s++) {
      int c = tid + 256 * s;
      int row = c >> 2, c4 = c & 3;
      size_t ga = (size_t)(m0 + row) * Kd + k0 + c4 * 8;
      *(uint4*)&Ah[row][c4 * 8] = *(const uint4*)&Ahi[ga];
      *(uint4*)&Al[row][c4 * 8] = *(const uint4*)&Alo[ga];
      int nrow = n0 + row;
      if (nrow < Nvalid) {
        size_t gb = (size_t)nrow * Kd + k0 + c4 * 8;
        *(uint4*)&Bh[row][c4 * 8] = *(const uint4*)&Bhi[gb];
        *(uint4*)&Bl[row][c4 * 8] = *(const uint4*)&Blo[gb];
      } else {
        uint4 z = make_uint4(0u, 0u, 0u, 0u);
        *(uint4*)&Bh[row][c4 * 8] = z;
        *(uint4*)&Bl[row][c4 * 8] = z;
      }
    }
    __syncthreads();
    bf16x8 bhf[4], blf[4];
#pragma unroll
    for (int nf = 0; nf < 4; nf++) {
      int r = wc * 64 + nf * 16 + fr;
      bhf[nf] = *(bf16x8*)&Bh[r][fo];
      blf[nf] = *(bf16x8*)&Bl[r][fo];
    }
#pragma unroll
    for (int mf = 0; mf < 4; mf++) {
      int r = wr * 64 + mf * 16 + fr;
      bf16x8 ahf = *(bf16x8*)&Ah[r][fo];
      bf16x8 alf = *(bf16x8*)&Al[r][fo];
#pragma unroll
      for (int nf = 0; nf < 4; nf++) {
        acc[mf][nf] = __builtin_amdgcn_mfma_f32_16x16x32_bf16(ahf, bhf[nf], acc[mf][nf], 0, 0, 0);
        acc[mf][nf] = __builtin_amdgcn_mfma_f32_16x16x32_bf16(ahf, blf[nf], acc[mf][nf], 0, 0, 0);
        acc[mf][nf] = __builtin_amdgcn_mfma_f32_16x16x32_bf16(alf, bhf[nf], acc[mf][nf], 0, 0, 0);
      }
    }
    __syncthreads();
  }
  // epilogue: D row = 4*(lane>>4)+r, col = lane&15 within each 16x16 frag
  const int rq = lane >> 4;
#pragma unroll
  for (int mf = 0; mf < 4; mf++) {
#pragma unroll
    for (int nf = 0; nf < 4; nf++) {
      int col = n0 + wc * 64 + nf * 16 + fr;
      if (col < Nvalid) {
        float bv = bias[col];
#pragma unroll
        for (int r = 0; r < 4; r++) {
          int m = m0 + wr * 64 + mf * 16 + rq * 4 + r;
          C[(size_t)m * ldc + col] = acc[mf][nf][r] + bv;
        }
      }
    }
  }
}

// ---------------------------------------------------------------------------
// Fused flash attention per head: grid = B*H*(T/16) = 4096 blocks.
// ---------------------------------------------------------------------------
__global__ __launch_bounds__(256) void attn_fused(
    const float* __restrict__ Cqkv, float* __restrict__ mrow,
    float* __restrict__ linv, float* __restrict__ out_pre) {
  __shared__ float Ks[64][68];
  __shared__ float Vs[64][68];
  __shared__ float Ps[16][68];
  const int bi = blockIdx.x;
  const int qt = bi & 63, h = (bi >> 6) & 15, b = bi >> 10;
  const int q0 = qt * 16, tid = threadIdx.x;
  const int q = tid >> 4, x16 = tid & 15;
  const float scale = 0.125f;
  float Qr[64];
  const float* qrow = &Cqkv[(size_t)(b * T_ + q0 + q) * NCAT + h * DH_];
#pragma unroll
  for (int d4 = 0; d4 < 16; d4++) {
    float4 v = *(const float4*)&qrow[d4 * 4];
    Qr[d4 * 4 + 0] = v.x; Qr[d4 * 4 + 1] = v.y;
    Qr[d4 * 4 + 2] = v.z; Qr[d4 * 4 + 3] = v.w;
  }
  float m_run = -1e30f, l_run = 0.f;
  float po[4] = {0.f, 0.f, 0.f, 0.f};
  for (int kt = 0; kt < 16; kt++) {
#pragma unroll
    for (int s = 0; s < 4; s++) {
      int i = tid + 256 * s;
      int r = i >> 4, c4 = i & 15;
      const float* krow = &Cqkv[(size_t)(b * T_ + kt * 64 + r) * NCAT];
      *(float4*)&Ks[r][c4 * 4] = *(const float4*)&krow[1024 + h * DH_ + c4 * 4];
      *(float4*)&Vs[r][c4 * 4] = *(const float4*)&krow[2048 + c4 * 4];
    }
    __syncthreads();
    float p[4];
    float tm = -1e30f;
#pragma unroll
    for (int jj = 0; jj < 4; jj++) {
      int kk = x16 + 16 * jj;
      float s = 0.f;
#pragma unroll
      for (int d4 = 0; d4 < 16; d4++) {
        float4 v = *(float4*)&Ks[kk][d4 * 4];
        s = fmaf(Qr[d4 * 4 + 0], v.x, s);
        s = fmaf(Qr[d4 * 4 + 1], v.y, s);
        s = fmaf(Qr[d4 * 4 + 2], v.z, s);
        s = fmaf(Qr[d4 * 4 + 3], v.w, s);
      }
      p[jj] = s * scale;
      tm = fmaxf(tm, p[jj]);
    }
#pragma unroll
    for (int off = 1; off < 16; off <<= 1)
      tm = fmaxf(tm, __shfl_xor(tm, off, 16));
    float m_new = fmaxf(m_run, tm);
    float c = __expf(m_run - m_new);
    float ts = 0.f;
#pragma unroll
    for (int jj = 0; jj < 4; jj++) {
      p[jj] = __expf(p[jj] - m_new);
      ts += p[jj];
      Ps[q][x16 + 16 * jj] = p[jj];
    }
#pragma unroll
    for (int off = 1; off < 16; off <<= 1)
      ts += __shfl_xor(ts, off, 16);
    l_run = l_run * c + ts;
    m_run = m_new;
    __syncthreads();
#pragma unroll
    for (int jj = 0; jj < 4; jj++) po[jj] *= c;
#pragma unroll
    for (int kk = 0; kk < 64; kk++) {
      float pp = Ps[q][kk];
      float4 v = *(float4*)&Vs[kk][x16 * 4];
      po[0] = fmaf(pp, v.x, po[0]);
      po[1] = fmaf(pp, v.y, po[1]);
      po[2] = fmaf(pp, v.z, po[2]);
      po[3] = fmaf(pp, v.w, po[3]);
    }
    __syncthreads();
  }
  const float li = 1.0f / l_run;
  if (x16 == 0) {
    int idx = (b * H_ + h) * T_ + q0 + q;
    mrow[idx] = m_run;
    linv[idx] = li;
  }
  int col = h * DH_ + x16 * 4;
  float4 o;
  o.x = po[0] * li; o.y = po[1] * li; o.z = po[2] * li; o.w = po[3] * li;
  *(float4*)&out_pre[((size_t)b * T_ + q0 + q) * D_ + col] = o;
}

// ---------------------------------------------------------------------------
// attn_mean: grid = B*(T/16)*(T/64) = 4096 blocks, 16x64 slice each.
// ---------------------------------------------------------------------------
__global__ __launch_bounds__(256) void attn_mean_k(
    const float* __restrict__ Cqkv, const float* __restrict__ mrow,
    const float* __restrict__ linv, float* __restrict__ am_out) {
  __shared__ float Ks[64][68];
  const int bi = blockIdx.x;
  const int kc = bi & 15, qt = (bi >> 4) & 63, b = bi >> 10;
  const int q0 = qt * 16, k0 = kc * 64, tid = threadIdx.x;
  const int q = tid >> 4, kg = tid & 15;
  const float scale = 0.125f;
  float am4[4] = {0.f, 0.f, 0.f, 0.f};
  for (int h = 0; h < H_; h++) {
#pragma unroll
    for (int s = 0; s < 4; s++) {
      int i = tid + 256 * s;
      int r = i >> 4, c4 = i & 15;
      *(float4*)&Ks[r][c4 * 4] =
          *(const float4*)&Cqkv[(size_t)(b * T_ + k0 + r) * NCAT + 1024 + h * DH_ + c4 * 4];
    }
    __syncthreads();
    const float mq = mrow[(b * H_ + h) * T_ + q0 + q];
    const float li = linv[(b * H_ + h) * T_ + q0 + q];
    const float* qrow = &Cqkv[(size_t)(b * T_ + q0 + q) * NCAT + h * DH_];
    float Qr[64];
#pragma unroll
    for (int d4 = 0; d4 < 16; d4++) {
      float4 v = *(const float4*)&qrow[d4 * 4];
      Qr[d4 * 4 + 0] = v.x; Qr[d4 * 4 + 1] = v.y;
      Qr[d4 * 4 + 2] = v.z; Qr[d4 * 4 + 3] = v.w;
    }
#pragma unroll
    for (int jj = 0; jj < 4; jj++) {
      int kk = kg + 16 * jj;
      float s = 0.f;
#pragma unroll
      for (int d4 = 0; d4 < 16; d4++) {
        float4 v = *(float4*)&Ks[kk][d4 * 4];
        s = fmaf(Qr[d4 * 4 + 0], v.x, s);
        s = fmaf(Qr[d4 * 4 + 1], v.y, s);
        s = fmaf(Qr[d4 * 4 + 2], v.z, s);
        s = fmaf(Qr[d4 * 4 + 3], v.w, s);
      }
      am4[jj] += __expf(s * scale - mq) * li;
    }
    __syncthreads();
  }
#pragma unroll
  for (int jj = 0; jj < 4; jj++) {
    int k = k0 + kg + 16 * jj;
    am_out[((size_t)b * T_ + q0 + q) * T_ + k] = am4[jj] * (1.0f / 16.0f);
  }
}

// ---------------------------------------------------------------------------
extern "C" void kernel_launch(void* const* d_in, const int* in_sizes, int n_in,
                              void* d_out, int out_size, void* d_ws, size_t ws_size,
                              hipStream_t stream) {
  const float* x  = (const float*)d_in[0];
  const float* Wq = (const float*)d_in[1];
  const float* bq = (const float*)d_in[2];
  const float* Wk = (const float*)d_in[3];
  const float* bk = (const float*)d_in[4];
  const float* Wv = (const float*)d_in[5];
  const float* bv = (const float*)d_in[6];
  const float* Wo = (const float*)d_in[7];
  const float* bo = (const float*)d_in[8];

  float* out = (float*)d_out;                      // [B,T,D]
  float* am  = out + (size_t)B_ * T_ * D_;         // [B,T,T]

  char* w = (char*)d_ws;
  float* Cqkv    = (float*)w; w += (size_t)4096 * NCAT * 4;
  float* mrow    = (float*)w; w += (size_t)B_ * H_ * T_ * 4;
  float* linvp   = (float*)w; w += (size_t)B_ * H_ * T_ * 4;
  float* out_pre = (float*)w; w += (size_t)4096 * 1024 * 4;
  float* bcat    = (float*)w; w += (size_t)NCAT * 4;
  u16* xhi   = (u16*)w; w += (size_t)4096 * 1024 * 2;  // reused as out_pre hi
  u16* xlo   = (u16*)w; w += (size_t)4096 * 1024 * 2;  // reused as out_pre lo
  u16* WcThi = (u16*)w; w += (size_t)NCAT * 1024 * 2;
  u16* WcTlo = (u16*)w; w += (size_t)NCAT * 1024 * 2;
  u16* WoThi = (u16*)w; w += (size_t)1024 * 1024 * 2;
  u16* WoTlo = (u16*)w; w += (size_t)1024 * 1024 * 2;

  // weight transpose + split-convert (B^T layout: [n][k])
  tconv<<<dim3(16, 16), 256, 0, stream>>>(Wq, 1024, WcThi, WcTlo, 0);
  tconv<<<dim3(16, 16), 256, 0, stream>>>(Wk, 1024, WcThi, WcTlo, 1024);
  tconv<<<dim3(1, 16),  256, 0, stream>>>(Wv,   64, WcThi, WcTlo, 2048);
  tconv<<<dim3(16, 16), 256, 0, stream>>>(Wo, 1024, WoThi, WoTlo, 0);
  bias_concat<<<9, 256, 0, stream>>>(bq, bk, bv, bcat);
  rowconv<<<2048, 256, 0, stream>>>(x, xhi, xlo);

  mfma_gemm<<<dim3(32, 17), 256, 0, stream>>>(xhi, xlo, WcThi, WcTlo, bcat,
                                              Cqkv, NCAT, 1024, NCAT);
  attn_fused<<<B_ * H_ * (T_ / 16), 256, 0, stream>>>(Cqkv, mrow, linvp, out_pre);
  attn_mean_k<<<B_ * (T_ / 16) * (T_ / 64), 256, 0, stream>>>(Cqkv, mrow, linvp, am);
  rowconv<<<2048, 256, 0, stream>>>(out_pre, xhi, xlo);
  mfma_gemm<<<dim3(32, 8), 256, 0, stream>>>(xhi, xlo, WoThi, WoTlo, bo,
                                             out, 1024, 1024, 1024);
}

// Round 5
// 290.963 us; speedup vs baseline: 9.4651x; 2.5026x over previous
//
#include <hip/hip_runtime.h>
#include <math.h>

#define B_ 4
#define T_ 1024
#define D_ 1024
#define H_ 16
#define DH_ 64
#define NCAT 2112   // 1024 (Q) + 1024 (K) + 64 (V)

typedef unsigned short u16;
typedef unsigned int u32;
typedef __attribute__((ext_vector_type(8))) short bf16x8;
typedef __attribute__((ext_vector_type(4))) float f32x4;

union U8 { bf16x8 v; u32 u[4]; };

__device__ __forceinline__ u16 bf16rne(float f) {
  u32 u = __float_as_uint(f);
  u32 r = (u + 0x7fffu + ((u >> 16) & 1u)) >> 16;
  return (u16)r;
}
__device__ __forceinline__ float bf16tof(u16 h) {
  return __uint_as_float((u32)h << 16);
}

// ---------------------------------------------------------------------------
// Transpose + split-convert: W fp32 [K=1024][Nw] -> Thi/Tlo bf16 [roff+n][1024]
// ---------------------------------------------------------------------------
__global__ __launch_bounds__(256) void tconv(
    const float* __restrict__ W, int Nw,
    u16* __restrict__ Thi, u16* __restrict__ Tlo, int roff) {
  __shared__ float Ws[64][65];
  const int t = threadIdx.x;
  const int n0 = blockIdx.x * 64, k0 = blockIdx.y * 64;
#pragma unroll
  for (int rr = 0; rr < 4; rr++) {
    int r = rr * 16 + (t >> 4);
    int c = (t & 15) * 4;
    float4 v = *(const float4*)&W[(size_t)(k0 + r) * Nw + n0 + c];
    Ws[r][c] = v.x; Ws[r][c + 1] = v.y; Ws[r][c + 2] = v.z; Ws[r][c + 3] = v.w;
  }
  __syncthreads();
  const int n = t >> 2, kc = t & 3;
  u32 uh[8], ul[8];
#pragma unroll
  for (int j2 = 0; j2 < 8; j2++) {
    u16 hh[2], ll[2];
#pragma unroll
    for (int e = 0; e < 2; e++) {
      float v = Ws[kc * 16 + j2 * 2 + e][n];
      u16 h = bf16rne(v);
      hh[e] = h;
      ll[e] = bf16rne(v - bf16tof(h));
    }
    uh[j2] = (u32)hh[0] | ((u32)hh[1] << 16);
    ul[j2] = (u32)ll[0] | ((u32)ll[1] << 16);
  }
  size_t base = (size_t)(roff + n0 + n) * 1024 + k0 + kc * 16;
  *(uint4*)&Thi[base]     = make_uint4(uh[0], uh[1], uh[2], uh[3]);
  *(uint4*)&Thi[base + 8] = make_uint4(uh[4], uh[5], uh[6], uh[7]);
  *(uint4*)&Tlo[base]     = make_uint4(ul[0], ul[1], ul[2], ul[3]);
  *(uint4*)&Tlo[base + 8] = make_uint4(ul[4], ul[5], ul[6], ul[7]);
}

// ---------------------------------------------------------------------------
// Row-major split-convert: in fp32 [4096*1024] -> hi/lo bf16, same layout.
// ---------------------------------------------------------------------------
__global__ __launch_bounds__(256) void rowconv(
    const float* __restrict__ in, u16* __restrict__ hi, u16* __restrict__ lo) {
  size_t i = ((size_t)blockIdx.x * 256 + threadIdx.x) * 8;
  float4 v0 = *(const float4*)&in[i];
  float4 v1 = *(const float4*)&in[i + 4];
  float vv[8] = {v0.x, v0.y, v0.z, v0.w, v1.x, v1.y, v1.z, v1.w};
  u32 uh[4], ul[4];
#pragma unroll
  for (int j = 0; j < 4; j++) {
    u16 h0 = bf16rne(vv[2 * j]);
    u16 h1 = bf16rne(vv[2 * j + 1]);
    u16 l0 = bf16rne(vv[2 * j] - bf16tof(h0));
    u16 l1 = bf16rne(vv[2 * j + 1] - bf16tof(h1));
    uh[j] = (u32)h0 | ((u32)h1 << 16);
    ul[j] = (u32)l0 | ((u32)l1 << 16);
  }
  *(uint4*)&hi[i] = make_uint4(uh[0], uh[1], uh[2], uh[3]);
  *(uint4*)&lo[i] = make_uint4(ul[0], ul[1], ul[2], ul[3]);
}

__global__ __launch_bounds__(256) void bias_concat(
    const float* __restrict__ bq, const float* __restrict__ bk,
    const float* __restrict__ bv, float* __restrict__ bcat) {
  int i = blockIdx.x * 256 + threadIdx.x;
  if (i < NCAT)
    bcat[i] = (i < 1024) ? bq[i] : ((i < 2048) ? bk[i - 1024] : bv[i - 2048]);
}

// ---------------------------------------------------------------------------
// K-block split: Cqkv cols 1024..2047 fp32 -> Khi/Klo bf16 [4096][1024]
// ---------------------------------------------------------------------------
__global__ __launch_bounds__(256) void ksplit(
    const float* __restrict__ Cqkv, u16* __restrict__ Khi, u16* __restrict__ Klo) {
  size_t i = ((size_t)blockIdx.x * 256 + threadIdx.x) * 8;
  size_t row = i >> 10, col = i & 1023;
  const float* src = &Cqkv[row * NCAT + 1024 + col];
  float4 v0 = *(const float4*)&src[0];
  float4 v1 = *(const float4*)&src[4];
  float vv[8] = {v0.x, v0.y, v0.z, v0.w, v1.x, v1.y, v1.z, v1.w};
  u32 uh[4], ul[4];
#pragma unroll
  for (int j = 0; j < 4; j++) {
    u16 h0 = bf16rne(vv[2 * j]);
    u16 h1 = bf16rne(vv[2 * j + 1]);
    u16 l0 = bf16rne(vv[2 * j] - bf16tof(h0));
    u16 l1 = bf16rne(vv[2 * j + 1] - bf16tof(h1));
    uh[j] = (u32)h0 | ((u32)h1 << 16);
    ul[j] = (u32)l0 | ((u32)l1 << 16);
  }
  *(uint4*)&Khi[i] = make_uint4(uh[0], uh[1], uh[2], uh[3]);
  *(uint4*)&Klo[i] = make_uint4(ul[0], ul[1], ul[2], ul[3]);
}

// ---------------------------------------------------------------------------
// V transpose + bf16: Cqkv cols 2048..2111 fp32 [4096][64] -> Vt bf16 [64][4096]
// ---------------------------------------------------------------------------
__global__ __launch_bounds__(256) void vsplit(
    const float* __restrict__ Cqkv, u16* __restrict__ Vt) {
  __shared__ float Vs[64][65];
  const int bt0 = blockIdx.x * 64;
  const int t = threadIdx.x;
  {
    int r = t >> 2, c = (t & 3) * 16;
#pragma unroll
    for (int j = 0; j < 4; j++) {
      float4 v = *(const float4*)&Cqkv[(size_t)(bt0 + r) * NCAT + 2048 + c + 4 * j];
      Vs[r][c + 4 * j] = v.x; Vs[r][c + 4 * j + 1] = v.y;
      Vs[r][c + 4 * j + 2] = v.z; Vs[r][c + 4 * j + 3] = v.w;
    }
  }
  __syncthreads();
  const int dh = t >> 2, kk = (t & 3) * 16;
  u32 uw[8];
#pragma unroll
  for (int j = 0; j < 8; j++) {
    u16 a = bf16rne(Vs[kk + 2 * j][dh]);
    u16 b = bf16rne(Vs[kk + 2 * j + 1][dh]);
    uw[j] = (u32)a | ((u32)b << 16);
  }
  size_t base = (size_t)dh * 4096 + bt0 + kk;
  *(uint4*)&Vt[base]     = make_uint4(uw[0], uw[1], uw[2], uw[3]);
  *(uint4*)&Vt[base + 8] = make_uint4(uw[4], uw[5], uw[6], uw[7]);
}

// ---------------------------------------------------------------------------
// Split-bf16 MFMA GEMM + bias (validated round 4).
// ---------------------------------------------------------------------------
__global__ __launch_bounds__(256) void mfma_gemm(
    const u16* __restrict__ Ahi, const u16* __restrict__ Alo,
    const u16* __restrict__ Bhi, const u16* __restrict__ Blo,
    const float* __restrict__ bias, float* __restrict__ C,
    int Nvalid, int Kd, int ldc) {
  __shared__ u16 Ah[128][40];
  __shared__ u16 Al[128][40];
  __shared__ u16 Bh[128][40];
  __shared__ u16 Bl[128][40];
  const int tid = threadIdx.x;
  const int lane = tid & 63, wid = tid >> 6;
  const int wr = wid >> 1, wc = wid & 1;
  const int m0 = blockIdx.x * 128, n0 = blockIdx.y * 128;
  f32x4 acc[4][4];
#pragma unroll
  for (int i = 0; i < 4; i++)
#pragma unroll
    for (int j = 0; j < 4; j++) {
      acc[i][j][0] = 0.f; acc[i][j][1] = 0.f;
      acc[i][j][2] = 0.f; acc[i][j][3] = 0.f;
    }
  const int fo = 8 * (lane >> 4);
  const int fr = lane & 15;

#pragma unroll 1
  for (int k0 = 0; k0 < Kd; k0 += 32) {
#pragma unroll
    for (int s = 0; s < 2; s++) {
      int c = tid + 256 * s;
      int row = c >> 2, c4 = c & 3;
      size_t ga = (size_t)(m0 + row) * Kd + k0 + c4 * 8;
      *(uint4*)&Ah[row][c4 * 8] = *(const uint4*)&Ahi[ga];
      *(uint4*)&Al[row][c4 * 8] = *(const uint4*)&Alo[ga];
      int nrow = n0 + row;
      if (nrow < Nvalid) {
        size_t gb = (size_t)nrow * Kd + k0 + c4 * 8;
        *(uint4*)&Bh[row][c4 * 8] = *(const uint4*)&Bhi[gb];
        *(uint4*)&Bl[row][c4 * 8] = *(const uint4*)&Blo[gb];
      } else {
        uint4 z = make_uint4(0u, 0u, 0u, 0u);
        *(uint4*)&Bh[row][c4 * 8] = z;
        *(uint4*)&Bl[row][c4 * 8] = z;
      }
    }
    __syncthreads();
    bf16x8 bhf[4], blf[4];
#pragma unroll
    for (int nf = 0; nf < 4; nf++) {
      int r = wc * 64 + nf * 16 + fr;
      bhf[nf] = *(bf16x8*)&Bh[r][fo];
      blf[nf] = *(bf16x8*)&Bl[r][fo];
    }
#pragma unroll
    for (int mf = 0; mf < 4; mf++) {
      int r = wr * 64 + mf * 16 + fr;
      bf16x8 ahf = *(bf16x8*)&Ah[r][fo];
      bf16x8 alf = *(bf16x8*)&Al[r][fo];
#pragma unroll
      for (int nf = 0; nf < 4; nf++) {
        acc[mf][nf] = __builtin_amdgcn_mfma_f32_16x16x32_bf16(ahf, bhf[nf], acc[mf][nf], 0, 0, 0);
        acc[mf][nf] = __builtin_amdgcn_mfma_f32_16x16x32_bf16(ahf, blf[nf], acc[mf][nf], 0, 0, 0);
        acc[mf][nf] = __builtin_amdgcn_mfma_f32_16x16x32_bf16(alf, bhf[nf], acc[mf][nf], 0, 0, 0);
      }
    }
    __syncthreads();
  }
  const int rq = lane >> 4;
#pragma unroll
  for (int mf = 0; mf < 4; mf++) {
#pragma unroll
    for (int nf = 0; nf < 4; nf++) {
      int col = n0 + wc * 64 + nf * 16 + fr;
      if (col < Nvalid) {
        float bv = bias[col];
#pragma unroll
        for (int r = 0; r < 4; r++) {
          int m = m0 + wr * 64 + mf * 16 + rq * 4 + r;
          C[(size_t)m * ldc + col] = acc[mf][nf][r] + bv;
        }
      }
    }
  }
}

// ---------------------------------------------------------------------------
// MFMA flash attention. grid = B*H*(T/64) = 1024 blocks, 256 thr (4 waves).
// Wave w owns 16 q rows. S via mfma(K,Q) 3-pass split: D[k][q], q=lane&15,
// k=16*mf+4*g+r. Softmax: in-lane + shfl_xor 16/32. P->bf16 via per-wave LDS
// round-trip to A-operand layout; PV via mfma(P,Vt) hi-only.
// ---------------------------------------------------------------------------
__global__ __launch_bounds__(256) void attn_fused_mfma(
    const float* __restrict__ Cqkv, const u16* __restrict__ Khi,
    const u16* __restrict__ Klo, const u16* __restrict__ Vt,
    float* __restrict__ mrow, float* __restrict__ linv,
    float* __restrict__ out_pre) {
  __shared__ u16 Kh_s[64][72];
  __shared__ u16 Kl_s[64][72];
  __shared__ u16 Vt_s[64][72];
  __shared__ u16 P_s[4][16][72];
  __shared__ float c_s[4][16];
  const int bi = blockIdx.x;
  const int qt = bi & 15, h = (bi >> 4) & 15, b = bi >> 8;
  const int tid = threadIdx.x;
  const int lane = tid & 63, w = tid >> 6;
  const int l15 = lane & 15, g = lane >> 4;
  const int q0 = qt * 64 + w * 16;
  const float scale = 0.125f;
  // Q fragments (hi/lo) from fp32 Cqkv, once per block
  bf16x8 qh[2], ql[2];
  {
    const float* qrow = &Cqkv[(size_t)(b * T_ + q0 + l15) * NCAT + h * DH_];
#pragma unroll
    for (int ks = 0; ks < 2; ks++) {
      float4 v0 = *(const float4*)&qrow[ks * 32 + 8 * g];
      float4 v1 = *(const float4*)&qrow[ks * 32 + 8 * g + 4];
      float vv[8] = {v0.x, v0.y, v0.z, v0.w, v1.x, v1.y, v1.z, v1.w};
      U8 H, L;
#pragma unroll
      for (int j = 0; j < 4; j++) {
        u16 h0 = bf16rne(vv[2 * j]);
        u16 h1 = bf16rne(vv[2 * j + 1]);
        u16 l0 = bf16rne(vv[2 * j] - bf16tof(h0));
        u16 l1 = bf16rne(vv[2 * j + 1] - bf16tof(h1));
        H.u[j] = (u32)h0 | ((u32)h1 << 16);
        L.u[j] = (u32)l0 | ((u32)l1 << 16);
      }
      qh[ks] = H.v; ql[ks] = L.v;
    }
  }
  float m_run = -1e30f, l_run = 0.f;
  f32x4 acc_o[4];
#pragma unroll
  for (int nf = 0; nf < 4; nf++) {
    acc_o[nf][0] = 0.f; acc_o[nf][1] = 0.f; acc_o[nf][2] = 0.f; acc_o[nf][3] = 0.f;
  }

#pragma unroll 1
  for (int kt = 0; kt < 16; kt++) {
    // stage K hi/lo + Vt tile
    {
      int r = tid >> 2, cs = (tid & 3) * 16;
      size_t krow = (size_t)(b * T_ + kt * 64 + r) * 1024 + h * DH_ + cs;
      *(uint4*)&Kh_s[r][cs]     = *(const uint4*)&Khi[krow];
      *(uint4*)&Kh_s[r][cs + 8] = *(const uint4*)&Khi[krow + 8];
      *(uint4*)&Kl_s[r][cs]     = *(const uint4*)&Klo[krow];
      *(uint4*)&Kl_s[r][cs + 8] = *(const uint4*)&Klo[krow + 8];
      size_t vrow = (size_t)r * 4096 + b * T_ + kt * 64 + cs;
      *(uint4*)&Vt_s[r][cs]     = *(const uint4*)&Vt[vrow];
      *(uint4*)&Vt_s[r][cs + 8] = *(const uint4*)&Vt[vrow + 8];
    }
    __syncthreads();
    // S: 3-pass split MFMA, D[k][q]
    f32x4 accs[4];
#pragma unroll
    for (int mf = 0; mf < 4; mf++) {
      accs[mf][0] = 0.f; accs[mf][1] = 0.f; accs[mf][2] = 0.f; accs[mf][3] = 0.f;
    }
#pragma unroll
    for (int mf = 0; mf < 4; mf++) {
#pragma unroll
      for (int ks = 0; ks < 2; ks++) {
        bf16x8 kh = *(bf16x8*)&Kh_s[mf * 16 + l15][ks * 32 + 8 * g];
        bf16x8 kl = *(bf16x8*)&Kl_s[mf * 16 + l15][ks * 32 + 8 * g];
        accs[mf] = __builtin_amdgcn_mfma_f32_16x16x32_bf16(kh, qh[ks], accs[mf], 0, 0, 0);
        accs[mf] = __builtin_amdgcn_mfma_f32_16x16x32_bf16(kh, ql[ks], accs[mf], 0, 0, 0);
        accs[mf] = __builtin_amdgcn_mfma_f32_16x16x32_bf16(kl, qh[ks], accs[mf], 0, 0, 0);
      }
    }
    // softmax over this tile's 64 k for q = l15
    float tm = -1e30f;
#pragma unroll
    for (int mf = 0; mf < 4; mf++)
#pragma unroll
      for (int r = 0; r < 4; r++) {
        accs[mf][r] *= scale;
        tm = fmaxf(tm, accs[mf][r]);
      }
    tm = fmaxf(tm, __shfl_xor(tm, 16));
    tm = fmaxf(tm, __shfl_xor(tm, 32));
    float m_new = fmaxf(m_run, tm);
    float crs = __expf(m_run - m_new);
    float ts = 0.f;
#pragma unroll
    for (int mf = 0; mf < 4; mf++) {
      float p0 = __expf(accs[mf][0] - m_new);
      float p1 = __expf(accs[mf][1] - m_new);
      float p2 = __expf(accs[mf][2] - m_new);
      float p3 = __expf(accs[mf][3] - m_new);
      ts += (p0 + p1) + (p2 + p3);
      u32 w0 = (u32)bf16rne(p0) | ((u32)bf16rne(p1) << 16);
      u32 w1 = (u32)bf16rne(p2) | ((u32)bf16rne(p3) << 16);
      *(uint2*)&P_s[w][l15][16 * mf + 4 * g] = make_uint2(w0, w1);
    }
    ts += __shfl_xor(ts, 16);
    ts += __shfl_xor(ts, 32);
    l_run = l_run * crs + ts;
    m_run = m_new;
    if (g == 0) c_s[w][l15] = crs;
    __syncthreads();
    // PV: rescale acc, then mfma(P, Vt)
    float4 cc = *(float4*)&c_s[w][4 * g];
    float cca[4] = {cc.x, cc.y, cc.z, cc.w};
#pragma unroll
    for (int nf = 0; nf < 4; nf++)
#pragma unroll
      for (int r = 0; r < 4; r++) acc_o[nf][r] *= cca[r];
    bf16x8 pa[2];
    pa[0] = *(bf16x8*)&P_s[w][l15][8 * g];
    pa[1] = *(bf16x8*)&P_s[w][l15][32 + 8 * g];
#pragma unroll
    for (int nf = 0; nf < 4; nf++) {
#pragma unroll
      for (int ks = 0; ks < 2; ks++) {
        bf16x8 vb = *(bf16x8*)&Vt_s[nf * 16 + l15][ks * 32 + 8 * g];
        acc_o[nf] = __builtin_amdgcn_mfma_f32_16x16x32_bf16(pa[ks], vb, acc_o[nf], 0, 0, 0);
      }
    }
    __syncthreads();
  }
  float li = 1.0f / l_run;
  if (g == 0) {
    int idx = (b * H_ + h) * T_ + q0 + l15;
    mrow[idx] = m_run;
    linv[idx] = li;
    c_s[w][l15] = li;
  }
  __syncthreads();
  float4 lc = *(float4*)&c_s[w][4 * g];
  float lca[4] = {lc.x, lc.y, lc.z, lc.w};
#pragma unroll
  for (int nf = 0; nf < 4; nf++)
#pragma unroll
    for (int r = 0; r < 4; r++)
      out_pre[(size_t)(b * T_ + q0 + 4 * g + r) * D_ + h * DH_ + nf * 16 + l15] =
          acc_o[nf][r] * lca[r];
}

// ---------------------------------------------------------------------------
// MFMA attn_mean. grid = B*(T/64)*(T/64) = 1024 blocks. Wave w: q rows
// qt*64+w*16..+15, k cols kc*64..+63; loops h, accumulates exp(S-m)*linv.
// ---------------------------------------------------------------------------
__global__ __launch_bounds__(256) void attn_mean_mfma(
    const float* __restrict__ Cqkv, const u16* __restrict__ Khi,
    const u16* __restrict__ Klo, const float* __restrict__ mrow,
    const float* __restrict__ linv, float* __restrict__ am_out) {
  __shared__ u16 Kh_s[64][72];
  __shared__ u16 Kl_s[64][72];
  const int bi = blockIdx.x;
  const int kc = bi & 15, qt = (bi >> 4) & 15, b = bi >> 8;
  const int tid = threadIdx.x;
  const int lane = tid & 63, w = tid >> 6;
  const int l15 = lane & 15, g = lane >> 4;
  const int q0 = qt * 64 + w * 16, k0 = kc * 64;
  const float scale = 0.125f;
  float am[4][4] = {};
#pragma unroll 1
  for (int h = 0; h < H_; h++) {
    {
      int r = tid >> 2, cs = (tid & 3) * 16;
      size_t krow = (size_t)(b * T_ + k0 + r) * 1024 + h * DH_ + cs;
      *(uint4*)&Kh_s[r][cs]     = *(const uint4*)&Khi[krow];
      *(uint4*)&Kh_s[r][cs + 8] = *(const uint4*)&Khi[krow + 8];
      *(uint4*)&Kl_s[r][cs]     = *(const uint4*)&Klo[krow];
      *(uint4*)&Kl_s[r][cs + 8] = *(const uint4*)&Klo[krow + 8];
    }
    __syncthreads();
    bf16x8 qh[2], ql[2];
    {
      const float* qrow = &Cqkv[(size_t)(b * T_ + q0 + l15) * NCAT + h * DH_];
#pragma unroll
      for (int ks = 0; ks < 2; ks++) {
        float4 v0 = *(const float4*)&qrow[ks * 32 + 8 * g];
        float4 v1 = *(const float4*)&qrow[ks * 32 + 8 * g + 4];
        float vv[8] = {v0.x, v0.y, v0.z, v0.w, v1.x, v1.y, v1.z, v1.w};
        U8 H, L;
#pragma unroll
        for (int j = 0; j < 4; j++) {
          u16 h0 = bf16rne(vv[2 * j]);
          u16 h1 = bf16rne(vv[2 * j + 1]);
          u16 l0 = bf16rne(vv[2 * j] - bf16tof(h0));
          u16 l1 = bf16rne(vv[2 * j + 1] - bf16tof(h1));
          H.u[j] = (u32)h0 | ((u32)h1 << 16);
          L.u[j] = (u32)l0 | ((u32)l1 << 16);
        }
        qh[ks] = H.v; ql[ks] = L.v;
      }
    }
    f32x4 accs[4];
#pragma unroll
    for (int mf = 0; mf < 4; mf++) {
      accs[mf][0] = 0.f; accs[mf][1] = 0.f; accs[mf][2] = 0.f; accs[mf][3] = 0.f;
    }
#pragma unroll
    for (int mf = 0; mf < 4; mf++) {
#pragma unroll
      for (int ks = 0; ks < 2; ks++) {
        bf16x8 kh = *(bf16x8*)&Kh_s[mf * 16 + l15][ks * 32 + 8 * g];
        bf16x8 kl = *(bf16x8*)&Kl_s[mf * 16 + l15][ks * 32 + 8 * g];
        accs[mf] = __builtin_amdgcn_mfma_f32_16x16x32_bf16(kh, qh[ks], accs[mf], 0, 0, 0);
        accs[mf] = __builtin_amdgcn_mfma_f32_16x16x32_bf16(kh, ql[ks], accs[mf], 0, 0, 0);
        accs[mf] = __builtin_amdgcn_mfma_f32_16x16x32_bf16(kl, qh[ks], accs[mf], 0, 0, 0);
      }
    }
    const float mq = mrow[(b * H_ + h) * T_ + q0 + l15];
    const float li = linv[(b * H_ + h) * T_ + q0 + l15];
#pragma unroll
    for (int mf = 0; mf < 4; mf++)
#pragma unroll
      for (int r = 0; r < 4; r++)
        am[mf][r] += __expf(accs[mf][r] * scale - mq) * li;
    __syncthreads();
  }
  const float inv16 = 1.0f / 16.0f;
#pragma unroll
  for (int mf = 0; mf < 4; mf++) {
    float4 o;
    o.x = am[mf][0] * inv16; o.y = am[mf][1] * inv16;
    o.z = am[mf][2] * inv16; o.w = am[mf][3] * inv16;
    *(float4*)&am_out[(size_t)(b * T_ + q0 + l15) * T_ + k0 + 16 * mf + 4 * g] = o;
  }
}

// ---------------------------------------------------------------------------
extern "C" void kernel_launch(void* const* d_in, const int* in_sizes, int n_in,
                              void* d_out, int out_size, void* d_ws, size_t ws_size,
                              hipStream_t stream) {
  const float* x  = (const float*)d_in[0];
  const float* Wq = (const float*)d_in[1];
  const float* bq = (const float*)d_in[2];
  const float* Wk = (const float*)d_in[3];
  const float* bk = (const float*)d_in[4];
  const float* Wv = (const float*)d_in[5];
  const float* bv = (const float*)d_in[6];
  const float* Wo = (const float*)d_in[7];
  const float* bo = (const float*)d_in[8];

  float* out = (float*)d_out;                      // [B,T,D]
  float* am  = out + (size_t)B_ * T_ * D_;         // [B,T,T]

  char* w = (char*)d_ws;
  float* Cqkv    = (float*)w; w += (size_t)4096 * NCAT * 4;
  float* mrow    = (float*)w; w += (size_t)B_ * H_ * T_ * 4;
  float* linvp   = (float*)w; w += (size_t)B_ * H_ * T_ * 4;
  float* out_pre = (float*)w; w += (size_t)4096 * 1024 * 4;
  float* bcat    = (float*)w; w += (size_t)NCAT * 4;
  u16* xhi   = (u16*)w; w += (size_t)4096 * 1024 * 2;  // x-split, then K hi, then out_pre hi
  u16* xlo   = (u16*)w; w += (size_t)4096 * 1024 * 2;  // x-split, then K lo, then out_pre lo
  u16* WcThi = (u16*)w; w += (size_t)NCAT * 1024 * 2;
  u16* WcTlo = (u16*)w; w += (size_t)NCAT * 1024 * 2;
  u16* WoThi = (u16*)w; w += (size_t)1024 * 1024 * 2;
  u16* WoTlo = (u16*)w; w += (size_t)1024 * 1024 * 2;
  u16* Vt    = (u16*)w; w += (size_t)64 * 4096 * 2;

  // weight transpose + split-convert (B^T layout: [n][k])
  tconv<<<dim3(16, 16), 256, 0, stream>>>(Wq, 1024, WcThi, WcTlo, 0);
  tconv<<<dim3(16, 16), 256, 0, stream>>>(Wk, 1024, WcThi, WcTlo, 1024);
  tconv<<<dim3(1, 16),  256, 0, stream>>>(Wv,   64, WcThi, WcTlo, 2048);
  tconv<<<dim3(16, 16), 256, 0, stream>>>(Wo, 1024, WoThi, WoTlo, 0);
  bias_concat<<<9, 256, 0, stream>>>(bq, bk, bv, bcat);
  rowconv<<<2048, 256, 0, stream>>>(x, xhi, xlo);

  mfma_gemm<<<dim3(32, 17), 256, 0, stream>>>(xhi, xlo, WcThi, WcTlo, bcat,
                                              Cqkv, NCAT, 1024, NCAT);
  // K/V low-precision prep (xhi/xlo reused as Khi/Klo)
  ksplit<<<2048, 256, 0, stream>>>(Cqkv, xhi, xlo);
  vsplit<<<64, 256, 0, stream>>>(Cqkv, Vt);

  attn_fused_mfma<<<1024, 256, 0, stream>>>(Cqkv, xhi, xlo, Vt,
                                            mrow, linvp, out_pre);
  attn_mean_mfma<<<1024, 256, 0, stream>>>(Cqkv, xhi, xlo, mrow, linvp, am);

  rowconv<<<2048, 256, 0, stream>>>(out_pre, xhi, xlo);
  mfma_gemm<<<dim3(32, 8), 256, 0, stream>>>(xhi, xlo, WoThi, WoTlo, bo,
                                             out, 1024, 1024, 1024);
}

// Round 6
// 263.598 us; speedup vs baseline: 10.4478x; 1.1038x over previous
//
#include <hip/hip_runtime.h>
#include <math.h>

#define B_ 4
#define T_ 1024
#define D_ 1024
#define H_ 16
#define DH_ 64
#define NCAT 2112   // 1024 (Q) + 1024 (K) + 64 (V)
#define KSTR (2 * NCAT)  // Cqkv row stride in u16 units (4224)

typedef unsigned short u16;
typedef unsigned int u32;
typedef __attribute__((ext_vector_type(8))) short bf16x8;
typedef __attribute__((ext_vector_type(4))) float f32x4;

union U8 { bf16x8 v; u32 u[4]; };

__device__ __forceinline__ u16 bf16rne(float f) {
  u32 u = __float_as_uint(f);
  u32 r = (u + 0x7fffu + ((u >> 16) & 1u)) >> 16;
  return (u16)r;
}
__device__ __forceinline__ float bf16tof(u16 h) {
  return __uint_as_float((u32)h << 16);
}

// ---------------------------------------------------------------------------
// Transpose + split-convert: W fp32 [K=1024][Nw] -> Thi/Tlo bf16 [roff+n][1024]
// ---------------------------------------------------------------------------
__global__ __launch_bounds__(256) void tconv(
    const float* __restrict__ W, int Nw,
    u16* __restrict__ Thi, u16* __restrict__ Tlo, int roff) {
  __shared__ float Ws[64][65];
  const int t = threadIdx.x;
  const int n0 = blockIdx.x * 64, k0 = blockIdx.y * 64;
#pragma unroll
  for (int rr = 0; rr < 4; rr++) {
    int r = rr * 16 + (t >> 4);
    int c = (t & 15) * 4;
    float4 v = *(const float4*)&W[(size_t)(k0 + r) * Nw + n0 + c];
    Ws[r][c] = v.x; Ws[r][c + 1] = v.y; Ws[r][c + 2] = v.z; Ws[r][c + 3] = v.w;
  }
  __syncthreads();
  const int n = t >> 2, kc = t & 3;
  u32 uh[8], ul[8];
#pragma unroll
  for (int j2 = 0; j2 < 8; j2++) {
    u16 hh[2], ll[2];
#pragma unroll
    for (int e = 0; e < 2; e++) {
      float v = Ws[kc * 16 + j2 * 2 + e][n];
      u16 h = bf16rne(v);
      hh[e] = h;
      ll[e] = bf16rne(v - bf16tof(h));
    }
    uh[j2] = (u32)hh[0] | ((u32)hh[1] << 16);
    ul[j2] = (u32)ll[0] | ((u32)ll[1] << 16);
  }
  size_t base = (size_t)(roff + n0 + n) * 1024 + k0 + kc * 16;
  *(uint4*)&Thi[base]     = make_uint4(uh[0], uh[1], uh[2], uh[3]);
  *(uint4*)&Thi[base + 8] = make_uint4(uh[4], uh[5], uh[6], uh[7]);
  *(uint4*)&Tlo[base]     = make_uint4(ul[0], ul[1], ul[2], ul[3]);
  *(uint4*)&Tlo[base + 8] = make_uint4(ul[4], ul[5], ul[6], ul[7]);
}

// ---------------------------------------------------------------------------
// Row-major split-convert: in fp32 [4096*1024] -> hi/lo bf16, same layout.
// ---------------------------------------------------------------------------
__global__ __launch_bounds__(256) void rowconv(
    const float* __restrict__ in, u16* __restrict__ hi, u16* __restrict__ lo) {
  size_t i = ((size_t)blockIdx.x * 256 + threadIdx.x) * 8;
  float4 v0 = *(const float4*)&in[i];
  float4 v1 = *(const float4*)&in[i + 4];
  float vv[8] = {v0.x, v0.y, v0.z, v0.w, v1.x, v1.y, v1.z, v1.w};
  u32 uh[4], ul[4];
#pragma unroll
  for (int j = 0; j < 4; j++) {
    u16 h0 = bf16rne(vv[2 * j]);
    u16 h1 = bf16rne(vv[2 * j + 1]);
    u16 l0 = bf16rne(vv[2 * j] - bf16tof(h0));
    u16 l1 = bf16rne(vv[2 * j + 1] - bf16tof(h1));
    uh[j] = (u32)h0 | ((u32)h1 << 16);
    ul[j] = (u32)l0 | ((u32)l1 << 16);
  }
  *(uint4*)&hi[i] = make_uint4(uh[0], uh[1], uh[2], uh[3]);
  *(uint4*)&lo[i] = make_uint4(ul[0], ul[1], ul[2], ul[3]);
}

__global__ __launch_bounds__(256) void bias_concat(
    const float* __restrict__ bq, const float* __restrict__ bk,
    const float* __restrict__ bv, float* __restrict__ bcat) {
  int i = blockIdx.x * 256 + threadIdx.x;
  if (i < NCAT)
    bcat[i] = (i < 1024) ? bq[i] : ((i < 2048) ? bk[i - 1024] : bv[i - 2048]);
}

// ---------------------------------------------------------------------------
// V transpose + bf16: Cqkv cols 2048..2111 fp32 [4096][64] -> Vt bf16 [64][4096]
// ---------------------------------------------------------------------------
__global__ __launch_bounds__(256) void vsplit(
    const float* __restrict__ Cqkv, u16* __restrict__ Vt) {
  __shared__ float Vs[64][65];
  const int bt0 = blockIdx.x * 64;
  const int t = threadIdx.x;
  {
    int r = t >> 2, c = (t & 3) * 16;
#pragma unroll
    for (int j = 0; j < 4; j++) {
      float4 v = *(const float4*)&Cqkv[(size_t)(bt0 + r) * NCAT + 2048 + c + 4 * j];
      Vs[r][c + 4 * j] = v.x; Vs[r][c + 4 * j + 1] = v.y;
      Vs[r][c + 4 * j + 2] = v.z; Vs[r][c + 4 * j + 3] = v.w;
    }
  }
  __syncthreads();
  const int dh = t >> 2, kk = (t & 3) * 16;
  u32 uw[8];
#pragma unroll
  for (int j = 0; j < 8; j++) {
    u16 a = bf16rne(Vs[kk + 2 * j][dh]);
    u16 b = bf16rne(Vs[kk + 2 * j + 1][dh]);
    uw[j] = (u32)a | ((u32)b << 16);
  }
  size_t base = (size_t)dh * 4096 + bt0 + kk;
  *(uint4*)&Vt[base]     = make_uint4(uw[0], uw[1], uw[2], uw[3]);
  *(uint4*)&Vt[base + 8] = make_uint4(uw[4], uw[5], uw[6], uw[7]);
}

// ---------------------------------------------------------------------------
// Split-bf16 MFMA GEMM + bias. 64x128 tile (M x N), BK=32, 256 thr = 4 waves
// (2x2), wave = 32x64. If Kemb != nullptr (QKV GEMM): cols [1024,2048) are
// written as bf16 into the embedded Khi region (Cqkv u16 +2048/row) instead
// of fp32 C.
// ---------------------------------------------------------------------------
__global__ __launch_bounds__(256) void mfma_gemm(
    const u16* __restrict__ Ahi, const u16* __restrict__ Alo,
    const u16* __restrict__ Bhi, const u16* __restrict__ Blo,
    const float* __restrict__ bias, float* __restrict__ C,
    int Nvalid, int Kd, int ldc, u16* __restrict__ Kemb) {
  __shared__ u16 Ah[64][40];   // +8 pad: 80B stride -> 2-way bank (free)
  __shared__ u16 Al[64][40];
  __shared__ u16 Bh[128][40];
  __shared__ u16 Bl[128][40];
  const int tid = threadIdx.x;
  const int lane = tid & 63, wid = tid >> 6;
  const int wr = wid >> 1, wc = wid & 1;
  const int m0 = blockIdx.x * 64, n0 = blockIdx.y * 128;
  f32x4 acc[2][4];
#pragma unroll
  for (int i = 0; i < 2; i++)
#pragma unroll
    for (int j = 0; j < 4; j++) {
      acc[i][j][0] = 0.f; acc[i][j][1] = 0.f;
      acc[i][j][2] = 0.f; acc[i][j][3] = 0.f;
    }
  const int fo = 8 * (lane >> 4);
  const int fr = lane & 15;

#pragma unroll 1
  for (int k0 = 0; k0 < Kd; k0 += 32) {
    {  // A tile 64x32: one 16B chunk per thread per array
      int row = tid >> 2, c4 = tid & 3;
      size_t ga = (size_t)(m0 + row) * Kd + k0 + c4 * 8;
      *(uint4*)&Ah[row][c4 * 8] = *(const uint4*)&Ahi[ga];
      *(uint4*)&Al[row][c4 * 8] = *(const uint4*)&Alo[ga];
    }
#pragma unroll
    for (int s = 0; s < 2; s++) {  // B tile 128x32: two chunks per thread
      int c = tid + 256 * s;
      int row = c >> 2, c4 = c & 3;
      int nrow = n0 + row;
      if (nrow < Nvalid) {
        size_t gb = (size_t)nrow * Kd + k0 + c4 * 8;
        *(uint4*)&Bh[row][c4 * 8] = *(const uint4*)&Bhi[gb];
        *(uint4*)&Bl[row][c4 * 8] = *(const uint4*)&Blo[gb];
      } else {
        uint4 z = make_uint4(0u, 0u, 0u, 0u);
        *(uint4*)&Bh[row][c4 * 8] = z;
        *(uint4*)&Bl[row][c4 * 8] = z;
      }
    }
    __syncthreads();
    bf16x8 bhf[4], blf[4];
#pragma unroll
    for (int nf = 0; nf < 4; nf++) {
      int r = wc * 64 + nf * 16 + fr;
      bhf[nf] = *(bf16x8*)&Bh[r][fo];
      blf[nf] = *(bf16x8*)&Bl[r][fo];
    }
#pragma unroll
    for (int mf = 0; mf < 2; mf++) {
      int r = wr * 32 + mf * 16 + fr;
      bf16x8 ahf = *(bf16x8*)&Ah[r][fo];
      bf16x8 alf = *(bf16x8*)&Al[r][fo];
#pragma unroll
      for (int nf = 0; nf < 4; nf++) {
        acc[mf][nf] = __builtin_amdgcn_mfma_f32_16x16x32_bf16(ahf, bhf[nf], acc[mf][nf], 0, 0, 0);
        acc[mf][nf] = __builtin_amdgcn_mfma_f32_16x16x32_bf16(ahf, blf[nf], acc[mf][nf], 0, 0, 0);
        acc[mf][nf] = __builtin_amdgcn_mfma_f32_16x16x32_bf16(alf, bhf[nf], acc[mf][nf], 0, 0, 0);
      }
    }
    __syncthreads();
  }
  const int rq = lane >> 4;
#pragma unroll
  for (int mf = 0; mf < 2; mf++) {
#pragma unroll
    for (int nf = 0; nf < 4; nf++) {
      int col = n0 + wc * 64 + nf * 16 + fr;
      if (col < Nvalid) {
        float bv = bias[col];
        if (Kemb != nullptr && col >= 1024 && col < 2048) {
#pragma unroll
          for (int r = 0; r < 4; r++) {
            int m = m0 + wr * 32 + mf * 16 + rq * 4 + r;
            Kemb[(size_t)m * KSTR + 2048 + (col - 1024)] =
                bf16rne(acc[mf][nf][r] + bv);
          }
        } else {
#pragma unroll
          for (int r = 0; r < 4; r++) {
            int m = m0 + wr * 32 + mf * 16 + rq * 4 + r;
            C[(size_t)m * ldc + col] = acc[mf][nf][r] + bv;
          }
        }
      }
    }
  }
}

// ---------------------------------------------------------------------------
// MFMA flash attention. grid = B*H*(T/64) = 1024 blocks, 256 thr (4 waves).
// S via mfma(Kh, Qhi) + mfma(Kh, Qlo) (2-pass: K bf16, Q split). Khi is
// embedded in Cqkv (u16 +2048 per row, stride KSTR).
// ---------------------------------------------------------------------------
__global__ __launch_bounds__(256) void attn_fused_mfma(
    const float* __restrict__ Cqkv, const u16* __restrict__ Kemb,
    const u16* __restrict__ Vt, float* __restrict__ mrow,
    float* __restrict__ linv, float* __restrict__ out_pre) {
  __shared__ u16 Kh_s[64][72];
  __shared__ u16 Vt_s[64][72];
  __shared__ u16 P_s[4][16][72];
  __shared__ float c_s[4][16];
  const int bi = blockIdx.x;
  const int qt = bi & 15, h = (bi >> 4) & 15, b = bi >> 8;
  const int tid = threadIdx.x;
  const int lane = tid & 63, w = tid >> 6;
  const int l15 = lane & 15, g = lane >> 4;
  const int q0 = qt * 64 + w * 16;
  const float scale = 0.125f;
  bf16x8 qh[2], ql[2];
  {
    const float* qrow = &Cqkv[(size_t)(b * T_ + q0 + l15) * NCAT + h * DH_];
#pragma unroll
    for (int ks = 0; ks < 2; ks++) {
      float4 v0 = *(const float4*)&qrow[ks * 32 + 8 * g];
      float4 v1 = *(const float4*)&qrow[ks * 32 + 8 * g + 4];
      float vv[8] = {v0.x, v0.y, v0.z, v0.w, v1.x, v1.y, v1.z, v1.w};
      U8 H, L;
#pragma unroll
      for (int j = 0; j < 4; j++) {
        u16 h0 = bf16rne(vv[2 * j]);
        u16 h1 = bf16rne(vv[2 * j + 1]);
        u16 l0 = bf16rne(vv[2 * j] - bf16tof(h0));
        u16 l1 = bf16rne(vv[2 * j + 1] - bf16tof(h1));
        H.u[j] = (u32)h0 | ((u32)h1 << 16);
        L.u[j] = (u32)l0 | ((u32)l1 << 16);
      }
      qh[ks] = H.v; ql[ks] = L.v;
    }
  }
  float m_run = -1e30f, l_run = 0.f;
  f32x4 acc_o[4];
#pragma unroll
  for (int nf = 0; nf < 4; nf++) {
    acc_o[nf][0] = 0.f; acc_o[nf][1] = 0.f; acc_o[nf][2] = 0.f; acc_o[nf][3] = 0.f;
  }

#pragma unroll 1
  for (int kt = 0; kt < 16; kt++) {
    {
      int r = tid >> 2, cs = (tid & 3) * 16;
      size_t krow = (size_t)(b * T_ + kt * 64 + r) * KSTR + 2048 + h * DH_ + cs;
      // h*DH_ spans 0..960; K cols for head h at embedded offset h*64
      *(uint4*)&Kh_s[r][cs]     = *(const uint4*)&Kemb[krow];
      *(uint4*)&Kh_s[r][cs + 8] = *(const uint4*)&Kemb[krow + 8];
      size_t vrow = (size_t)r * 4096 + b * T_ + kt * 64 + cs;
      *(uint4*)&Vt_s[r][cs]     = *(const uint4*)&Vt[vrow];
      *(uint4*)&Vt_s[r][cs + 8] = *(const uint4*)&Vt[vrow + 8];
    }
    __syncthreads();
    f32x4 accs[4];
#pragma unroll
    for (int mf = 0; mf < 4; mf++) {
      accs[mf][0] = 0.f; accs[mf][1] = 0.f; accs[mf][2] = 0.f; accs[mf][3] = 0.f;
    }
#pragma unroll
    for (int mf = 0; mf < 4; mf++) {
#pragma unroll
      for (int ks = 0; ks < 2; ks++) {
        bf16x8 kh = *(bf16x8*)&Kh_s[mf * 16 + l15][ks * 32 + 8 * g];
        accs[mf] = __builtin_amdgcn_mfma_f32_16x16x32_bf16(kh, qh[ks], accs[mf], 0, 0, 0);
        accs[mf] = __builtin_amdgcn_mfma_f32_16x16x32_bf16(kh, ql[ks], accs[mf], 0, 0, 0);
      }
    }
    float tm = -1e30f;
#pragma unroll
    for (int mf = 0; mf < 4; mf++)
#pragma unroll
      for (int r = 0; r < 4; r++) {
        accs[mf][r] *= scale;
        tm = fmaxf(tm, accs[mf][r]);
      }
    tm = fmaxf(tm, __shfl_xor(tm, 16));
    tm = fmaxf(tm, __shfl_xor(tm, 32));
    float m_new = fmaxf(m_run, tm);
    float crs = __expf(m_run - m_new);
    float ts = 0.f;
#pragma unroll
    for (int mf = 0; mf < 4; mf++) {
      float p0 = __expf(accs[mf][0] - m_new);
      float p1 = __expf(accs[mf][1] - m_new);
      float p2 = __expf(accs[mf][2] - m_new);
      float p3 = __expf(accs[mf][3] - m_new);
      ts += (p0 + p1) + (p2 + p3);
      u32 w0 = (u32)bf16rne(p0) | ((u32)bf16rne(p1) << 16);
      u32 w1 = (u32)bf16rne(p2) | ((u32)bf16rne(p3) << 16);
      *(uint2*)&P_s[w][l15][16 * mf + 4 * g] = make_uint2(w0, w1);
    }
    ts += __shfl_xor(ts, 16);
    ts += __shfl_xor(ts, 32);
    l_run = l_run * crs + ts;
    m_run = m_new;
    if (g == 0) c_s[w][l15] = crs;
    __syncthreads();
    float4 cc = *(float4*)&c_s[w][4 * g];
    float cca[4] = {cc.x, cc.y, cc.z, cc.w};
#pragma unroll
    for (int nf = 0; nf < 4; nf++)
#pragma unroll
      for (int r = 0; r < 4; r++) acc_o[nf][r] *= cca[r];
    bf16x8 pa[2];
    pa[0] = *(bf16x8*)&P_s[w][l15][8 * g];
    pa[1] = *(bf16x8*)&P_s[w][l15][32 + 8 * g];
#pragma unroll
    for (int nf = 0; nf < 4; nf++) {
#pragma unroll
      for (int ks = 0; ks < 2; ks++) {
        bf16x8 vb = *(bf16x8*)&Vt_s[nf * 16 + l15][ks * 32 + 8 * g];
        acc_o[nf] = __builtin_amdgcn_mfma_f32_16x16x32_bf16(pa[ks], vb, acc_o[nf], 0, 0, 0);
      }
    }
    __syncthreads();
  }
  float li = 1.0f / l_run;
  if (g == 0) {
    int idx = (b * H_ + h) * T_ + q0 + l15;
    mrow[idx] = m_run;
    linv[idx] = li;
    c_s[w][l15] = li;
  }
  __syncthreads();
  float4 lc = *(float4*)&c_s[w][4 * g];
  float lca[4] = {lc.x, lc.y, lc.z, lc.w};
#pragma unroll
  for (int nf = 0; nf < 4; nf++)
#pragma unroll
    for (int r = 0; r < 4; r++)
      out_pre[(size_t)(b * T_ + q0 + 4 * g + r) * D_ + h * DH_ + nf * 16 + l15] =
          acc_o[nf][r] * lca[r];
}

// ---------------------------------------------------------------------------
// MFMA attn_mean. grid = B*(T/64)*(T/64) = 1024 blocks. 2-pass S, Khi embedded.
// ---------------------------------------------------------------------------
__global__ __launch_bounds__(256) void attn_mean_mfma(
    const float* __restrict__ Cqkv, const u16* __restrict__ Kemb,
    const float* __restrict__ mrow, const float* __restrict__ linv,
    float* __restrict__ am_out) {
  __shared__ u16 Kh_s[64][72];
  const int bi = blockIdx.x;
  const int kc = bi & 15, qt = (bi >> 4) & 15, b = bi >> 8;
  const int tid = threadIdx.x;
  const int lane = tid & 63, w = tid >> 6;
  const int l15 = lane & 15, g = lane >> 4;
  const int q0 = qt * 64 + w * 16, k0 = kc * 64;
  const float scale = 0.125f;
  float am[4][4] = {};
#pragma unroll 1
  for (int h = 0; h < H_; h++) {
    {
      int r = tid >> 2, cs = (tid & 3) * 16;
      size_t krow = (size_t)(b * T_ + k0 + r) * KSTR + 2048 + h * DH_ + cs;
      *(uint4*)&Kh_s[r][cs]     = *(const uint4*)&Kemb[krow];
      *(uint4*)&Kh_s[r][cs + 8] = *(const uint4*)&Kemb[krow + 8];
    }
    __syncthreads();
    bf16x8 qh[2], ql[2];
    {
      const float* qrow = &Cqkv[(size_t)(b * T_ + q0 + l15) * NCAT + h * DH_];
#pragma unroll
      for (int ks = 0; ks < 2; ks++) {
        float4 v0 = *(const float4*)&qrow[ks * 32 + 8 * g];
        float4 v1 = *(const float4*)&qrow[ks * 32 + 8 * g + 4];
        float vv[8] = {v0.x, v0.y, v0.z, v0.w, v1.x, v1.y, v1.z, v1.w};
        U8 H, L;
#pragma unroll
        for (int j = 0; j < 4; j++) {
          u16 h0 = bf16rne(vv[2 * j]);
          u16 h1 = bf16rne(vv[2 * j + 1]);
          u16 l0 = bf16rne(vv[2 * j] - bf16tof(h0));
          u16 l1 = bf16rne(vv[2 * j + 1] - bf16tof(h1));
          H.u[j] = (u32)h0 | ((u32)h1 << 16);
          L.u[j] = (u32)l0 | ((u32)l1 << 16);
        }
        qh[ks] = H.v; ql[ks] = L.v;
      }
    }
    f32x4 accs[4];
#pragma unroll
    for (int mf = 0; mf < 4; mf++) {
      accs[mf][0] = 0.f; accs[mf][1] = 0.f; accs[mf][2] = 0.f; accs[mf][3] = 0.f;
    }
#pragma unroll
    for (int mf = 0; mf < 4; mf++) {
#pragma unroll
      for (int ks = 0; ks < 2; ks++) {
        bf16x8 kh = *(bf16x8*)&Kh_s[mf * 16 + l15][ks * 32 + 8 * g];
        accs[mf] = __builtin_amdgcn_mfma_f32_16x16x32_bf16(kh, qh[ks], accs[mf], 0, 0, 0);
        accs[mf] = __builtin_amdgcn_mfma_f32_16x16x32_bf16(kh, ql[ks], accs[mf], 0, 0, 0);
      }
    }
    const float mq = mrow[(b * H_ + h) * T_ + q0 + l15];
    const float li = linv[(b * H_ + h) * T_ + q0 + l15];
#pragma unroll
    for (int mf = 0; mf < 4; mf++)
#pragma unroll
      for (int r = 0; r < 4; r++)
        am[mf][r] += __expf(accs[mf][r] * scale - mq) * li;
    __syncthreads();
  }
  const float inv16 = 1.0f / 16.0f;
#pragma unroll
  for (int mf = 0; mf < 4; mf++) {
    float4 o;
    o.x = am[mf][0] * inv16; o.y = am[mf][1] * inv16;
    o.z = am[mf][2] * inv16; o.w = am[mf][3] * inv16;
    *(float4*)&am_out[(size_t)(b * T_ + q0 + l15) * T_ + k0 + 16 * mf + 4 * g] = o;
  }
}

// ---------------------------------------------------------------------------
extern "C" void kernel_launch(void* const* d_in, const int* in_sizes, int n_in,
                              void* d_out, int out_size, void* d_ws, size_t ws_size,
                              hipStream_t stream) {
  const float* x  = (const float*)d_in[0];
  const float* Wq = (const float*)d_in[1];
  const float* bq = (const float*)d_in[2];
  const float* Wk = (const float*)d_in[3];
  const float* bk = (const float*)d_in[4];
  const float* Wv = (const float*)d_in[5];
  const float* bv = (const float*)d_in[6];
  const float* Wo = (const float*)d_in[7];
  const float* bo = (const float*)d_in[8];

  float* out = (float*)d_out;                      // [B,T,D]
  float* am  = out + (size_t)B_ * T_ * D_;         // [B,T,T]

  char* w = (char*)d_ws;
  float* Cqkv    = (float*)w; w += (size_t)4096 * NCAT * 4;  // Q fp32 | Khi bf16 (embedded) | V fp32
  float* mrow    = (float*)w; w += (size_t)B_ * H_ * T_ * 4;
  float* linvp   = (float*)w; w += (size_t)B_ * H_ * T_ * 4;
  float* out_pre = (float*)w; w += (size_t)4096 * 1024 * 4;
  float* bcat    = (float*)w; w += (size_t)NCAT * 4;
  u16* xhi   = (u16*)w; w += (size_t)4096 * 1024 * 2;  // x-split, then out_pre hi
  u16* xlo   = (u16*)w; w += (size_t)4096 * 1024 * 2;  // x-split, then out_pre lo
  u16* WcThi = (u16*)w; w += (size_t)NCAT * 1024 * 2;
  u16* WcTlo = (u16*)w; w += (size_t)NCAT * 1024 * 2;
  u16* WoThi = (u16*)w; w += (size_t)1024 * 1024 * 2;
  u16* WoTlo = (u16*)w; w += (size_t)1024 * 1024 * 2;
  u16* Vt    = (u16*)w; w += (size_t)64 * 4096 * 2;

  // weight transpose + split-convert (B^T layout: [n][k])
  tconv<<<dim3(16, 16), 256, 0, stream>>>(Wq, 1024, WcThi, WcTlo, 0);
  tconv<<<dim3(16, 16), 256, 0, stream>>>(Wk, 1024, WcThi, WcTlo, 1024);
  tconv<<<dim3(1, 16),  256, 0, stream>>>(Wv,   64, WcThi, WcTlo, 2048);
  tconv<<<dim3(16, 16), 256, 0, stream>>>(Wo, 1024, WoThi, WoTlo, 0);
  bias_concat<<<9, 256, 0, stream>>>(bq, bk, bv, bcat);
  rowconv<<<2048, 256, 0, stream>>>(x, xhi, xlo);

  // QKV GEMM: writes Q/V fp32 into Cqkv, K directly as embedded bf16
  mfma_gemm<<<dim3(64, 17), 256, 0, stream>>>(xhi, xlo, WcThi, WcTlo, bcat,
                                              Cqkv, NCAT, 1024, NCAT,
                                              (u16*)Cqkv);
  vsplit<<<64, 256, 0, stream>>>(Cqkv, Vt);

  attn_fused_mfma<<<1024, 256, 0, stream>>>(Cqkv, (const u16*)Cqkv, Vt,
                                            mrow, linvp, out_pre);
  attn_mean_mfma<<<1024, 256, 0, stream>>>(Cqkv, (const u16*)Cqkv,
                                           mrow, linvp, am);

  rowconv<<<2048, 256, 0, stream>>>(out_pre, xhi, xlo);
  mfma_gemm<<<dim3(64, 8), 256, 0, stream>>>(xhi, xlo, WoThi, WoTlo, bo,
                                             out, 1024, 1024, 1024, nullptr);
}

// Round 7
// 250.271 us; speedup vs baseline: 11.0041x; 1.0532x over previous
//
#include <hip/hip_runtime.h>
#include <math.h>

#define B_ 4
#define T_ 1024
#define D_ 1024
#define H_ 16
#define DH_ 64
#define NCAT 2112   // 1024 (Q) + 1024 (K) + 64 (V)
#define KSTR (2 * NCAT)  // Cqkv row stride in u16 units (4224)

typedef unsigned short u16;
typedef unsigned int u32;
typedef __attribute__((ext_vector_type(8))) short bf16x8;
typedef __attribute__((ext_vector_type(4))) float f32x4;

union U8 { bf16x8 v; u32 u[4]; };

__device__ __forceinline__ u16 bf16rne(float f) {
  u32 u = __float_as_uint(f);
  u32 r = (u + 0x7fffu + ((u >> 16) & 1u)) >> 16;
  return (u16)r;
}
__device__ __forceinline__ float bf16tof(u16 h) {
  return __uint_as_float((u32)h << 16);
}

// async global->LDS, 16B per lane; LDS dest = wave-uniform base + lane*16
__device__ __forceinline__ void gload_lds16(const u16* g, u16* l) {
  __builtin_amdgcn_global_load_lds(
      (const __attribute__((address_space(1))) unsigned int*)g,
      (__attribute__((address_space(3))) unsigned int*)l, 16, 0, 0);
}

// ---------------------------------------------------------------------------
// Transpose + split-convert: W fp32 [K=1024][Nw] -> Thi/Tlo bf16 [roff+n][1024]
// ---------------------------------------------------------------------------
__global__ __launch_bounds__(256) void tconv(
    const float* __restrict__ W, int Nw,
    u16* __restrict__ Thi, u16* __restrict__ Tlo, int roff) {
  __shared__ float Ws[64][65];
  const int t = threadIdx.x;
  const int n0 = blockIdx.x * 64, k0 = blockIdx.y * 64;
#pragma unroll
  for (int rr = 0; rr < 4; rr++) {
    int r = rr * 16 + (t >> 4);
    int c = (t & 15) * 4;
    float4 v = *(const float4*)&W[(size_t)(k0 + r) * Nw + n0 + c];
    Ws[r][c] = v.x; Ws[r][c + 1] = v.y; Ws[r][c + 2] = v.z; Ws[r][c + 3] = v.w;
  }
  __syncthreads();
  const int n = t >> 2, kc = t & 3;
  u32 uh[8], ul[8];
#pragma unroll
  for (int j2 = 0; j2 < 8; j2++) {
    u16 hh[2], ll[2];
#pragma unroll
    for (int e = 0; e < 2; e++) {
      float v = Ws[kc * 16 + j2 * 2 + e][n];
      u16 h = bf16rne(v);
      hh[e] = h;
      ll[e] = bf16rne(v - bf16tof(h));
    }
    uh[j2] = (u32)hh[0] | ((u32)hh[1] << 16);
    ul[j2] = (u32)ll[0] | ((u32)ll[1] << 16);
  }
  size_t base = (size_t)(roff + n0 + n) * 1024 + k0 + kc * 16;
  *(uint4*)&Thi[base]     = make_uint4(uh[0], uh[1], uh[2], uh[3]);
  *(uint4*)&Thi[base + 8] = make_uint4(uh[4], uh[5], uh[6], uh[7]);
  *(uint4*)&Tlo[base]     = make_uint4(ul[0], ul[1], ul[2], ul[3]);
  *(uint4*)&Tlo[base + 8] = make_uint4(ul[4], ul[5], ul[6], ul[7]);
}

// ---------------------------------------------------------------------------
// Row-major split-convert: in fp32 [4096*1024] -> hi/lo bf16, same layout.
// ---------------------------------------------------------------------------
__global__ __launch_bounds__(256) void rowconv(
    const float* __restrict__ in, u16* __restrict__ hi, u16* __restrict__ lo) {
  size_t i = ((size_t)blockIdx.x * 256 + threadIdx.x) * 8;
  float4 v0 = *(const float4*)&in[i];
  float4 v1 = *(const float4*)&in[i + 4];
  float vv[8] = {v0.x, v0.y, v0.z, v0.w, v1.x, v1.y, v1.z, v1.w};
  u32 uh[4], ul[4];
#pragma unroll
  for (int j = 0; j < 4; j++) {
    u16 h0 = bf16rne(vv[2 * j]);
    u16 h1 = bf16rne(vv[2 * j + 1]);
    u16 l0 = bf16rne(vv[2 * j] - bf16tof(h0));
    u16 l1 = bf16rne(vv[2 * j + 1] - bf16tof(h1));
    uh[j] = (u32)h0 | ((u32)h1 << 16);
    ul[j] = (u32)l0 | ((u32)l1 << 16);
  }
  *(uint4*)&hi[i] = make_uint4(uh[0], uh[1], uh[2], uh[3]);
  *(uint4*)&lo[i] = make_uint4(ul[0], ul[1], ul[2], ul[3]);
}

__global__ __launch_bounds__(256) void bias_concat(
    const float* __restrict__ bq, const float* __restrict__ bk,
    const float* __restrict__ bv, float* __restrict__ bcat) {
  int i = blockIdx.x * 256 + threadIdx.x;
  if (i < NCAT)
    bcat[i] = (i < 1024) ? bq[i] : ((i < 2048) ? bk[i - 1024] : bv[i - 2048]);
}

// ---------------------------------------------------------------------------
// V transpose + bf16: Cqkv cols 2048..2111 fp32 [4096][64] -> Vt bf16 [64][4096]
// ---------------------------------------------------------------------------
__global__ __launch_bounds__(256) void vsplit(
    const float* __restrict__ Cqkv, u16* __restrict__ Vt) {
  __shared__ float Vs[64][65];
  const int bt0 = blockIdx.x * 64;
  const int t = threadIdx.x;
  {
    int r = t >> 2, c = (t & 3) * 16;
#pragma unroll
    for (int j = 0; j < 4; j++) {
      float4 v = *(const float4*)&Cqkv[(size_t)(bt0 + r) * NCAT + 2048 + c + 4 * j];
      Vs[r][c + 4 * j] = v.x; Vs[r][c + 4 * j + 1] = v.y;
      Vs[r][c + 4 * j + 2] = v.z; Vs[r][c + 4 * j + 3] = v.w;
    }
  }
  __syncthreads();
  const int dh = t >> 2, kk = (t & 3) * 16;
  u32 uw[8];
#pragma unroll
  for (int j = 0; j < 8; j++) {
    u16 a = bf16rne(Vs[kk + 2 * j][dh]);
    u16 b = bf16rne(Vs[kk + 2 * j + 1][dh]);
    uw[j] = (u32)a | ((u32)b << 16);
  }
  size_t base = (size_t)dh * 4096 + bt0 + kk;
  *(uint4*)&Vt[base]     = make_uint4(uw[0], uw[1], uw[2], uw[3]);
  *(uint4*)&Vt[base + 8] = make_uint4(uw[4], uw[5], uw[6], uw[7]);
}

// ---------------------------------------------------------------------------
// Split-bf16 MFMA GEMM + bias, m97 structure: TM x 128 tile, BK=32,
// linear LDS + global_load_lds(16B) staging, 4 waves (2x2), 2-barrier loop.
// TM=128: wave=64x64 (QKV); TM=64: wave=32x64 (Wo).
// If Kemb != nullptr: cols [1024,2048) stored bf16 at Cqkv +2048 u16/row.
// ---------------------------------------------------------------------------
template <int TM>
__global__ __launch_bounds__(256) void mfma_gemm(
    const u16* __restrict__ Ahi, const u16* __restrict__ Alo,
    const u16* __restrict__ Bhi, const u16* __restrict__ Blo,
    const float* __restrict__ bias, float* __restrict__ C,
    int Nvalid, int Kd, int ldc, u16* __restrict__ Kemb) {
  constexpr int MF = TM / 32;   // M-fragments per wave (4 or 2)
  constexpr int AC = TM / 64;   // A 1KB-chunks per wave per array (2 or 1)
  __shared__ u16 Ah[TM][32];
  __shared__ u16 Al[TM][32];
  __shared__ u16 Bh[128][32];
  __shared__ u16 Bl[128][32];
  const int tid = threadIdx.x;
  const int lane = tid & 63, wid = tid >> 6;
  const int wr = wid >> 1, wc = wid & 1;
  const int m0 = blockIdx.x * TM, n0 = blockIdx.y * 128;
  f32x4 acc[MF][4];
#pragma unroll
  for (int i = 0; i < MF; i++)
#pragma unroll
    for (int j = 0; j < 4; j++) {
      acc[i][j][0] = 0.f; acc[i][j][1] = 0.f;
      acc[i][j][2] = 0.f; acc[i][j][3] = 0.f;
    }
  const int fo = 8 * (lane >> 4);
  const int fr = lane & 15;
  const int srow = lane >> 2;        // row within a 16-row chunk
  const int scol = (lane & 3) * 8;   // u16 col within BK=32

#pragma unroll 1
  for (int k0 = 0; k0 < Kd; k0 += 32) {
#pragma unroll
    for (int c = 0; c < AC; c++) {
      int chunk = wid * AC + c;
      size_t ga = (size_t)(m0 + chunk * 16 + srow) * Kd + k0 + scol;
      gload_lds16(&Ahi[ga], ((u16*)Ah) + chunk * 512);
      gload_lds16(&Alo[ga], ((u16*)Al) + chunk * 512);
    }
#pragma unroll
    for (int c = 0; c < 2; c++) {
      int chunk = wid * 2 + c;
      int grow = n0 + chunk * 16 + srow;
      if (grow >= Nvalid) grow = Nvalid - 1;  // clamp; epilogue masks
      size_t gb = (size_t)grow * Kd + k0 + scol;
      gload_lds16(&Bhi[gb], ((u16*)Bh) + chunk * 512);
      gload_lds16(&Blo[gb], ((u16*)Bl) + chunk * 512);
    }
    __syncthreads();
    bf16x8 bhf[4], blf[4];
#pragma unroll
    for (int nf = 0; nf < 4; nf++) {
      int r = wc * 64 + nf * 16 + fr;
      bhf[nf] = *(bf16x8*)&Bh[r][fo];
      blf[nf] = *(bf16x8*)&Bl[r][fo];
    }
#pragma unroll
    for (int mf = 0; mf < MF; mf++) {
      int r = wr * (TM / 2) + mf * 16 + fr;
      bf16x8 ahf = *(bf16x8*)&Ah[r][fo];
      bf16x8 alf = *(bf16x8*)&Al[r][fo];
#pragma unroll
      for (int nf = 0; nf < 4; nf++) {
        acc[mf][nf] = __builtin_amdgcn_mfma_f32_16x16x32_bf16(ahf, bhf[nf], acc[mf][nf], 0, 0, 0);
        acc[mf][nf] = __builtin_amdgcn_mfma_f32_16x16x32_bf16(ahf, blf[nf], acc[mf][nf], 0, 0, 0);
        acc[mf][nf] = __builtin_amdgcn_mfma_f32_16x16x32_bf16(alf, bhf[nf], acc[mf][nf], 0, 0, 0);
      }
    }
    __syncthreads();
  }
  const int rq = lane >> 4;
#pragma unroll
  for (int mf = 0; mf < MF; mf++) {
#pragma unroll
    for (int nf = 0; nf < 4; nf++) {
      int col = n0 + wc * 64 + nf * 16 + fr;
      if (col < Nvalid) {
        float bv = bias[col];
        if (Kemb != nullptr && col >= 1024 && col < 2048) {
#pragma unroll
          for (int r = 0; r < 4; r++) {
            int m = m0 + wr * (TM / 2) + mf * 16 + rq * 4 + r;
            Kemb[(size_t)m * KSTR + 2048 + (col - 1024)] =
                bf16rne(acc[mf][nf][r] + bv);
          }
        } else {
#pragma unroll
          for (int r = 0; r < 4; r++) {
            int m = m0 + wr * (TM / 2) + mf * 16 + rq * 4 + r;
            C[(size_t)m * ldc + col] = acc[mf][nf][r] + bv;
          }
        }
      }
    }
  }
}

// ---------------------------------------------------------------------------
// MFMA flash attention. grid = B*H*(T/64) = 1024 blocks, 256 thr (4 waves).
// S via mfma(Kh, Qhi) + mfma(Kh, Qlo). Khi embedded in Cqkv.
// Epilogue writes out_pre split hi/lo bf16 (feeds Wo GEMM directly).
// ---------------------------------------------------------------------------
__global__ __launch_bounds__(256) void attn_fused_mfma(
    const float* __restrict__ Cqkv, const u16* __restrict__ Kemb,
    const u16* __restrict__ Vt, float* __restrict__ mrow,
    float* __restrict__ linv, u16* __restrict__ ophi,
    u16* __restrict__ oplo) {
  __shared__ u16 Kh_s[64][72];
  __shared__ u16 Vt_s[64][72];
  __shared__ u16 P_s[4][16][72];
  __shared__ float c_s[4][16];
  const int bi = blockIdx.x;
  const int qt = bi & 15, h = (bi >> 4) & 15, b = bi >> 8;
  const int tid = threadIdx.x;
  const int lane = tid & 63, w = tid >> 6;
  const int l15 = lane & 15, g = lane >> 4;
  const int q0 = qt * 64 + w * 16;
  const float scale = 0.125f;
  bf16x8 qh[2], ql[2];
  {
    const float* qrow = &Cqkv[(size_t)(b * T_ + q0 + l15) * NCAT + h * DH_];
#pragma unroll
    for (int ks = 0; ks < 2; ks++) {
      float4 v0 = *(const float4*)&qrow[ks * 32 + 8 * g];
      float4 v1 = *(const float4*)&qrow[ks * 32 + 8 * g + 4];
      float vv[8] = {v0.x, v0.y, v0.z, v0.w, v1.x, v1.y, v1.z, v1.w};
      U8 Hh, Ll;
#pragma unroll
      for (int j = 0; j < 4; j++) {
        u16 h0 = bf16rne(vv[2 * j]);
        u16 h1 = bf16rne(vv[2 * j + 1]);
        u16 l0 = bf16rne(vv[2 * j] - bf16tof(h0));
        u16 l1 = bf16rne(vv[2 * j + 1] - bf16tof(h1));
        Hh.u[j] = (u32)h0 | ((u32)h1 << 16);
        Ll.u[j] = (u32)l0 | ((u32)l1 << 16);
      }
      qh[ks] = Hh.v; ql[ks] = Ll.v;
    }
  }
  float m_run = -1e30f, l_run = 0.f;
  f32x4 acc_o[4];
#pragma unroll
  for (int nf = 0; nf < 4; nf++) {
    acc_o[nf][0] = 0.f; acc_o[nf][1] = 0.f; acc_o[nf][2] = 0.f; acc_o[nf][3] = 0.f;
  }

#pragma unroll 1
  for (int kt = 0; kt < 16; kt++) {
    {
      int r = tid >> 2, cs = (tid & 3) * 16;
      size_t krow = (size_t)(b * T_ + kt * 64 + r) * KSTR + 2048 + h * DH_ + cs;
      *(uint4*)&Kh_s[r][cs]     = *(const uint4*)&Kemb[krow];
      *(uint4*)&Kh_s[r][cs + 8] = *(const uint4*)&Kemb[krow + 8];
      size_t vrow = (size_t)r * 4096 + b * T_ + kt * 64 + cs;
      *(uint4*)&Vt_s[r][cs]     = *(const uint4*)&Vt[vrow];
      *(uint4*)&Vt_s[r][cs + 8] = *(const uint4*)&Vt[vrow + 8];
    }
    __syncthreads();
    f32x4 accs[4];
#pragma unroll
    for (int mf = 0; mf < 4; mf++) {
      accs[mf][0] = 0.f; accs[mf][1] = 0.f; accs[mf][2] = 0.f; accs[mf][3] = 0.f;
    }
#pragma unroll
    for (int mf = 0; mf < 4; mf++) {
#pragma unroll
      for (int ks = 0; ks < 2; ks++) {
        bf16x8 kh = *(bf16x8*)&Kh_s[mf * 16 + l15][ks * 32 + 8 * g];
        accs[mf] = __builtin_amdgcn_mfma_f32_16x16x32_bf16(kh, qh[ks], accs[mf], 0, 0, 0);
        accs[mf] = __builtin_amdgcn_mfma_f32_16x16x32_bf16(kh, ql[ks], accs[mf], 0, 0, 0);
      }
    }
    float tm = -1e30f;
#pragma unroll
    for (int mf = 0; mf < 4; mf++)
#pragma unroll
      for (int r = 0; r < 4; r++) {
        accs[mf][r] *= scale;
        tm = fmaxf(tm, accs[mf][r]);
      }
    tm = fmaxf(tm, __shfl_xor(tm, 16));
    tm = fmaxf(tm, __shfl_xor(tm, 32));
    float m_new = fmaxf(m_run, tm);
    float crs = __expf(m_run - m_new);
    float ts = 0.f;
#pragma unroll
    for (int mf = 0; mf < 4; mf++) {
      float p0 = __expf(accs[mf][0] - m_new);
      float p1 = __expf(accs[mf][1] - m_new);
      float p2 = __expf(accs[mf][2] - m_new);
      float p3 = __expf(accs[mf][3] - m_new);
      ts += (p0 + p1) + (p2 + p3);
      u32 w0 = (u32)bf16rne(p0) | ((u32)bf16rne(p1) << 16);
      u32 w1 = (u32)bf16rne(p2) | ((u32)bf16rne(p3) << 16);
      *(uint2*)&P_s[w][l15][16 * mf + 4 * g] = make_uint2(w0, w1);
    }
    ts += __shfl_xor(ts, 16);
    ts += __shfl_xor(ts, 32);
    l_run = l_run * crs + ts;
    m_run = m_new;
    if (g == 0) c_s[w][l15] = crs;
    __syncthreads();
    float4 cc = *(float4*)&c_s[w][4 * g];
    float cca[4] = {cc.x, cc.y, cc.z, cc.w};
#pragma unroll
    for (int nf = 0; nf < 4; nf++)
#pragma unroll
      for (int r = 0; r < 4; r++) acc_o[nf][r] *= cca[r];
    bf16x8 pa[2];
    pa[0] = *(bf16x8*)&P_s[w][l15][8 * g];
    pa[1] = *(bf16x8*)&P_s[w][l15][32 + 8 * g];
#pragma unroll
    for (int nf = 0; nf < 4; nf++) {
#pragma unroll
      for (int ks = 0; ks < 2; ks++) {
        bf16x8 vb = *(bf16x8*)&Vt_s[nf * 16 + l15][ks * 32 + 8 * g];
        acc_o[nf] = __builtin_amdgcn_mfma_f32_16x16x32_bf16(pa[ks], vb, acc_o[nf], 0, 0, 0);
      }
    }
    __syncthreads();
  }
  float li = 1.0f / l_run;
  if (g == 0) {
    int idx = (b * H_ + h) * T_ + q0 + l15;
    mrow[idx] = m_run;
    linv[idx] = li;
    c_s[w][l15] = li;
  }
  __syncthreads();
  float4 lc = *(float4*)&c_s[w][4 * g];
  float lca[4] = {lc.x, lc.y, lc.z, lc.w};
#pragma unroll
  for (int nf = 0; nf < 4; nf++)
#pragma unroll
    for (int r = 0; r < 4; r++) {
      float v = acc_o[nf][r] * lca[r];
      u16 hh = bf16rne(v);
      u16 ll = bf16rne(v - bf16tof(hh));
      size_t idx = (size_t)(b * T_ + q0 + 4 * g + r) * D_ + h * DH_ + nf * 16 + l15;
      ophi[idx] = hh;
      oplo[idx] = ll;
    }
}

// ---------------------------------------------------------------------------
// MFMA attn_mean. grid = B*(T/64)*(T/64) = 1024 blocks. 2-pass S, Khi embedded.
// ---------------------------------------------------------------------------
__global__ __launch_bounds__(256) void attn_mean_mfma(
    const float* __restrict__ Cqkv, const u16* __restrict__ Kemb,
    const float* __restrict__ mrow, const float* __restrict__ linv,
    float* __restrict__ am_out) {
  __shared__ u16 Kh_s[64][72];
  const int bi = blockIdx.x;
  const int kc = bi & 15, qt = (bi >> 4) & 15, b = bi >> 8;
  const int tid = threadIdx.x;
  const int lane = tid & 63, w = tid >> 6;
  const int l15 = lane & 15, g = lane >> 4;
  const int q0 = qt * 64 + w * 16, k0 = kc * 64;
  const float scale = 0.125f;
  float am[4][4] = {};
#pragma unroll 1
  for (int h = 0; h < H_; h++) {
    {
      int r = tid >> 2, cs = (tid & 3) * 16;
      size_t krow = (size_t)(b * T_ + k0 + r) * KSTR + 2048 + h * DH_ + cs;
      *(uint4*)&Kh_s[r][cs]     = *(const uint4*)&Kemb[krow];
      *(uint4*)&Kh_s[r][cs + 8] = *(const uint4*)&Kemb[krow + 8];
    }
    __syncthreads();
    bf16x8 qh[2], ql[2];
    {
      const float* qrow = &Cqkv[(size_t)(b * T_ + q0 + l15) * NCAT + h * DH_];
#pragma unroll
      for (int ks = 0; ks < 2; ks++) {
        float4 v0 = *(const float4*)&qrow[ks * 32 + 8 * g];
        float4 v1 = *(const float4*)&qrow[ks * 32 + 8 * g + 4];
        float vv[8] = {v0.x, v0.y, v0.z, v0.w, v1.x, v1.y, v1.z, v1.w};
        U8 Hh, Ll;
#pragma unroll
        for (int j = 0; j < 4; j++) {
          u16 h0 = bf16rne(vv[2 * j]);
          u16 h1 = bf16rne(vv[2 * j + 1]);
          u16 l0 = bf16rne(vv[2 * j] - bf16tof(h0));
          u16 l1 = bf16rne(vv[2 * j + 1] - bf16tof(h1));
          Hh.u[j] = (u32)h0 | ((u32)h1 << 16);
          Ll.u[j] = (u32)l0 | ((u32)l1 << 16);
        }
        qh[ks] = Hh.v; ql[ks] = Ll.v;
      }
    }
    f32x4 accs[4];
#pragma unroll
    for (int mf = 0; mf < 4; mf++) {
      accs[mf][0] = 0.f; accs[mf][1] = 0.f; accs[mf][2] = 0.f; accs[mf][3] = 0.f;
    }
#pragma unroll
    for (int mf = 0; mf < 4; mf++) {
#pragma unroll
      for (int ks = 0; ks < 2; ks++) {
        bf16x8 kh = *(bf16x8*)&Kh_s[mf * 16 + l15][ks * 32 + 8 * g];
        accs[mf] = __builtin_amdgcn_mfma_f32_16x16x32_bf16(kh, qh[ks], accs[mf], 0, 0, 0);
        accs[mf] = __builtin_amdgcn_mfma_f32_16x16x32_bf16(kh, ql[ks], accs[mf], 0, 0, 0);
      }
    }
    const float mq = mrow[(b * H_ + h) * T_ + q0 + l15];
    const float li = linv[(b * H_ + h) * T_ + q0 + l15];
#pragma unroll
    for (int mf = 0; mf < 4; mf++)
#pragma unroll
      for (int r = 0; r < 4; r++)
        am[mf][r] += __expf(accs[mf][r] * scale - mq) * li;
    __syncthreads();
  }
  const float inv16 = 1.0f / 16.0f;
#pragma unroll
  for (int mf = 0; mf < 4; mf++) {
    float4 o;
    o.x = am[mf][0] * inv16; o.y = am[mf][1] * inv16;
    o.z = am[mf][2] * inv16; o.w = am[mf][3] * inv16;
    *(float4*)&am_out[(size_t)(b * T_ + q0 + l15) * T_ + k0 + 16 * mf + 4 * g] = o;
  }
}

// ---------------------------------------------------------------------------
extern "C" void kernel_launch(void* const* d_in, const int* in_sizes, int n_in,
                              void* d_out, int out_size, void* d_ws, size_t ws_size,
                              hipStream_t stream) {
  const float* x  = (const float*)d_in[0];
  const float* Wq = (const float*)d_in[1];
  const float* bq = (const float*)d_in[2];
  const float* Wk = (const float*)d_in[3];
  const float* bk = (const float*)d_in[4];
  const float* Wv = (const float*)d_in[5];
  const float* bv = (const float*)d_in[6];
  const float* Wo = (const float*)d_in[7];
  const float* bo = (const float*)d_in[8];

  float* out = (float*)d_out;                      // [B,T,D]
  float* am  = out + (size_t)B_ * T_ * D_;         // [B,T,T]

  char* w = (char*)d_ws;
  float* Cqkv    = (float*)w; w += (size_t)4096 * NCAT * 4;  // Q fp32 | Khi bf16 (embedded) | V fp32
  float* mrow    = (float*)w; w += (size_t)B_ * H_ * T_ * 4;
  float* linvp   = (float*)w; w += (size_t)B_ * H_ * T_ * 4;
  float* bcat    = (float*)w; w += (size_t)NCAT * 4;
  u16* xhi   = (u16*)w; w += (size_t)4096 * 1024 * 2;  // x-split, then out_pre hi
  u16* xlo   = (u16*)w; w += (size_t)4096 * 1024 * 2;  // x-split, then out_pre lo
  u16* WcThi = (u16*)w; w += (size_t)NCAT * 1024 * 2;
  u16* WcTlo = (u16*)w; w += (size_t)NCAT * 1024 * 2;
  u16* WoThi = (u16*)w; w += (size_t)1024 * 1024 * 2;
  u16* WoTlo = (u16*)w; w += (size_t)1024 * 1024 * 2;
  u16* Vt    = (u16*)w; w += (size_t)64 * 4096 * 2;

  // weight transpose + split-convert (B^T layout: [n][k])
  tconv<<<dim3(16, 16), 256, 0, stream>>>(Wq, 1024, WcThi, WcTlo, 0);
  tconv<<<dim3(16, 16), 256, 0, stream>>>(Wk, 1024, WcThi, WcTlo, 1024);
  tconv<<<dim3(1, 16),  256, 0, stream>>>(Wv,   64, WcThi, WcTlo, 2048);
  tconv<<<dim3(16, 16), 256, 0, stream>>>(Wo, 1024, WoThi, WoTlo, 0);
  bias_concat<<<9, 256, 0, stream>>>(bq, bk, bv, bcat);
  rowconv<<<2048, 256, 0, stream>>>(x, xhi, xlo);

  // QKV GEMM: writes Q/V fp32 into Cqkv, K directly as embedded bf16
  mfma_gemm<128><<<dim3(32, 17), 256, 0, stream>>>(
      xhi, xlo, WcThi, WcTlo, bcat, Cqkv, NCAT, 1024, NCAT, (u16*)Cqkv);
  vsplit<<<64, 256, 0, stream>>>(Cqkv, Vt);

  // attention: writes out_pre directly as split bf16 into xhi/xlo
  attn_fused_mfma<<<1024, 256, 0, stream>>>(Cqkv, (const u16*)Cqkv, Vt,
                                            mrow, linvp, xhi, xlo);
  attn_mean_mfma<<<1024, 256, 0, stream>>>(Cqkv, (const u16*)Cqkv,
                                           mrow, linvp, am);

  mfma_gemm<64><<<dim3(64, 8), 256, 0, stream>>>(
      xhi, xlo, WoThi, WoTlo, bo, out, 1024, 1024, 1024, nullptr);
}

// Round 8
// 233.310 us; speedup vs baseline: 11.8041x; 1.0727x over previous
//
#include <hip/hip_runtime.h>
#include <math.h>

#define B_ 4
#define T_ 1024
#define D_ 1024
#define H_ 16
#define DH_ 64
#define NCAT 2112   // 1024 (Q) + 1024 (K) + 64 (V)

typedef unsigned short u16;
typedef unsigned int u32;
typedef __attribute__((ext_vector_type(8))) short bf16x8;
typedef __attribute__((ext_vector_type(4))) float f32x4;

__device__ __forceinline__ u16 bf16rne(float f) {
  u32 u = __float_as_uint(f);
  u32 r = (u + 0x7fffu + ((u >> 16) & 1u)) >> 16;
  return (u16)r;
}
__device__ __forceinline__ float bf16tof(u16 h) {
  return __uint_as_float((u32)h << 16);
}

// async global->LDS, 16B per lane; LDS dest = wave-uniform base + lane*16
__device__ __forceinline__ void gload_lds16(const u16* g, u16* l) {
  __builtin_amdgcn_global_load_lds(
      (const __attribute__((address_space(1))) unsigned int*)g,
      (__attribute__((address_space(3))) unsigned int*)l, 16, 0, 0);
}

// ---------------------------------------------------------------------------
// wprep: all weight transposes + split-converts + bias concat in ONE launch.
// blocks 0..255: Wq -> WcT[0..1023]; 256..511: Wk -> WcT[1024..2047];
// 512..767: Wo -> WoT; 768..783: Wv -> WcT[2048..2111]; 784: biases.
// ---------------------------------------------------------------------------
__global__ __launch_bounds__(256) void wprep(
    const float* __restrict__ Wq, const float* __restrict__ Wk,
    const float* __restrict__ Wv, const float* __restrict__ Wo,
    const float* __restrict__ bq, const float* __restrict__ bk,
    const float* __restrict__ bv,
    u16* __restrict__ WcThi, u16* __restrict__ WcTlo,
    u16* __restrict__ WoThi, u16* __restrict__ WoTlo,
    float* __restrict__ bcat) {
  const int blk = blockIdx.x;
  if (blk == 784) {
    for (int i = threadIdx.x; i < NCAT; i += 256)
      bcat[i] = (i < 1024) ? bq[i] : ((i < 2048) ? bk[i - 1024] : bv[i - 2048]);
    return;
  }
  const float* W;
  u16 *Thi, *Tlo;
  int roff, Nw, bx, by;
  if (blk < 256)      { W = Wq; Thi = WcThi; Tlo = WcTlo; roff = 0;    Nw = 1024; bx = blk & 15;        by = blk >> 4; }
  else if (blk < 512) { W = Wk; Thi = WcThi; Tlo = WcTlo; roff = 1024; Nw = 1024; bx = (blk - 256) & 15; by = (blk - 256) >> 4; }
  else if (blk < 768) { W = Wo; Thi = WoThi; Tlo = WoTlo; roff = 0;    Nw = 1024; bx = (blk - 512) & 15; by = (blk - 512) >> 4; }
  else                { W = Wv; Thi = WcThi; Tlo = WcTlo; roff = 2048; Nw = 64;   bx = 0;               by = blk - 768; }

  __shared__ float Ws[64][65];
  const int t = threadIdx.x;
  const int n0 = bx * 64, k0 = by * 64;
#pragma unroll
  for (int rr = 0; rr < 4; rr++) {
    int r = rr * 16 + (t >> 4);
    int c = (t & 15) * 4;
    float4 v = *(const float4*)&W[(size_t)(k0 + r) * Nw + n0 + c];
    Ws[r][c] = v.x; Ws[r][c + 1] = v.y; Ws[r][c + 2] = v.z; Ws[r][c + 3] = v.w;
  }
  __syncthreads();
  const int n = t >> 2, kc = t & 3;
  u32 uh[8], ul[8];
#pragma unroll
  for (int j2 = 0; j2 < 8; j2++) {
    u16 hh[2], ll[2];
#pragma unroll
    for (int e = 0; e < 2; e++) {
      float v = Ws[kc * 16 + j2 * 2 + e][n];
      u16 h = bf16rne(v);
      hh[e] = h;
      ll[e] = bf16rne(v - bf16tof(h));
    }
    uh[j2] = (u32)hh[0] | ((u32)hh[1] << 16);
    ul[j2] = (u32)ll[0] | ((u32)ll[1] << 16);
  }
  size_t base = (size_t)(roff + n0 + n) * 1024 + k0 + kc * 16;
  *(uint4*)&Thi[base]     = make_uint4(uh[0], uh[1], uh[2], uh[3]);
  *(uint4*)&Thi[base + 8] = make_uint4(uh[4], uh[5], uh[6], uh[7]);
  *(uint4*)&Tlo[base]     = make_uint4(ul[0], ul[1], ul[2], ul[3]);
  *(uint4*)&Tlo[base + 8] = make_uint4(ul[4], ul[5], ul[6], ul[7]);
}

// ---------------------------------------------------------------------------
// Row-major split-convert: in fp32 [4096*1024] -> hi/lo bf16, same layout.
// ---------------------------------------------------------------------------
__global__ __launch_bounds__(256) void rowconv(
    const float* __restrict__ in, u16* __restrict__ hi, u16* __restrict__ lo) {
  size_t i = ((size_t)blockIdx.x * 256 + threadIdx.x) * 8;
  float4 v0 = *(const float4*)&in[i];
  float4 v1 = *(const float4*)&in[i + 4];
  float vv[8] = {v0.x, v0.y, v0.z, v0.w, v1.x, v1.y, v1.z, v1.w};
  u32 uh[4], ul[4];
#pragma unroll
  for (int j = 0; j < 4; j++) {
    u16 h0 = bf16rne(vv[2 * j]);
    u16 h1 = bf16rne(vv[2 * j + 1]);
    u16 l0 = bf16rne(vv[2 * j] - bf16tof(h0));
    u16 l1 = bf16rne(vv[2 * j + 1] - bf16tof(h1));
    uh[j] = (u32)h0 | ((u32)h1 << 16);
    ul[j] = (u32)l0 | ((u32)l1 << 16);
  }
  *(uint4*)&hi[i] = make_uint4(uh[0], uh[1], uh[2], uh[3]);
  *(uint4*)&lo[i] = make_uint4(ul[0], ul[1], ul[2], ul[3]);
}

// ---------------------------------------------------------------------------
// Split-bf16 MFMA GEMM, m97-style staging (global_load_lds 16B, linear LDS),
// TM x 128 tile, BK=32, 4 waves (2x2).
// QKV=true: A panels y<8 (Q cols) 3-pass -> Qhi/Qlo bf16; y>=8 (K/V cols)
// 2-pass (drop Al@Bh; skip Al staging) -> Khi / Vt bf16 directly.
// QKV=false: 3-pass everywhere, fp32 C + bias (Wo projection).
// ---------------------------------------------------------------------------
template <int TM, bool QKV>
__global__ __launch_bounds__(256) void mfma_gemm(
    const u16* __restrict__ Ahi, const u16* __restrict__ Alo,
    const u16* __restrict__ Bhi, const u16* __restrict__ Blo,
    const float* __restrict__ bias, float* __restrict__ C,
    int Nvalid, int Kd, int ldc,
    u16* __restrict__ Qhi, u16* __restrict__ Qlo,
    u16* __restrict__ Khi, u16* __restrict__ Vt) {
  constexpr int MF = TM / 32;   // M-fragments per wave
  constexpr int AC = TM / 64;   // A 1KB-chunks per wave per array
  __shared__ u16 Ah[TM][32];
  __shared__ u16 Al[TM][32];
  __shared__ u16 Bh[128][32];
  __shared__ u16 Bl[128][32];
  const int tid = threadIdx.x;
  const int lane = tid & 63, wid = tid >> 6;
  const int wr = wid >> 1, wc = wid & 1;
  const int m0 = blockIdx.x * TM, n0 = blockIdx.y * 128;
  const bool full3 = !QKV || (blockIdx.y < 8);
  f32x4 acc[MF][4];
#pragma unroll
  for (int i = 0; i < MF; i++)
#pragma unroll
    for (int j = 0; j < 4; j++) {
      acc[i][j][0] = 0.f; acc[i][j][1] = 0.f;
      acc[i][j][2] = 0.f; acc[i][j][3] = 0.f;
    }
  const int fo = 8 * (lane >> 4);
  const int fr = lane & 15;
  const int srow = lane >> 2;        // row within a 16-row chunk
  const int scol = (lane & 3) * 8;   // u16 col within BK=32

#pragma unroll 1
  for (int k0 = 0; k0 < Kd; k0 += 32) {
#pragma unroll
    for (int c = 0; c < AC; c++) {
      int chunk = wid * AC + c;
      size_t ga = (size_t)(m0 + chunk * 16 + srow) * Kd + k0 + scol;
      gload_lds16(&Ahi[ga], ((u16*)Ah) + chunk * 512);
      if (full3) gload_lds16(&Alo[ga], ((u16*)Al) + chunk * 512);
    }
#pragma unroll
    for (int c = 0; c < 2; c++) {
      int chunk = wid * 2 + c;
      int grow = n0 + chunk * 16 + srow;
      if (grow >= Nvalid) grow = Nvalid - 1;  // clamp; epilogue masks
      size_t gb = (size_t)grow * Kd + k0 + scol;
      gload_lds16(&Bhi[gb], ((u16*)Bh) + chunk * 512);
      gload_lds16(&Blo[gb], ((u16*)Bl) + chunk * 512);
    }
    __syncthreads();
    bf16x8 bhf[4], blf[4];
#pragma unroll
    for (int nf = 0; nf < 4; nf++) {
      int r = wc * 64 + nf * 16 + fr;
      bhf[nf] = *(bf16x8*)&Bh[r][fo];
      blf[nf] = *(bf16x8*)&Bl[r][fo];
    }
#pragma unroll
    for (int mf = 0; mf < MF; mf++) {
      int r = wr * (TM / 2) + mf * 16 + fr;
      bf16x8 ahf = *(bf16x8*)&Ah[r][fo];
#pragma unroll
      for (int nf = 0; nf < 4; nf++) {
        acc[mf][nf] = __builtin_amdgcn_mfma_f32_16x16x32_bf16(ahf, bhf[nf], acc[mf][nf], 0, 0, 0);
        acc[mf][nf] = __builtin_amdgcn_mfma_f32_16x16x32_bf16(ahf, blf[nf], acc[mf][nf], 0, 0, 0);
      }
      if (full3) {
        bf16x8 alf = *(bf16x8*)&Al[r][fo];
#pragma unroll
        for (int nf = 0; nf < 4; nf++)
          acc[mf][nf] = __builtin_amdgcn_mfma_f32_16x16x32_bf16(alf, bhf[nf], acc[mf][nf], 0, 0, 0);
      }
    }
    __syncthreads();
  }
  const int rq = lane >> 4;
#pragma unroll
  for (int mf = 0; mf < MF; mf++) {
#pragma unroll
    for (int nf = 0; nf < 4; nf++) {
      int col = n0 + wc * 64 + nf * 16 + fr;
      if (col < Nvalid) {
        float bv = bias[col];
#pragma unroll
        for (int r = 0; r < 4; r++) {
          int m = m0 + wr * (TM / 2) + mf * 16 + rq * 4 + r;
          float v = acc[mf][nf][r] + bv;
          if constexpr (QKV) {
            if (col < 1024) {            // Q: split hi/lo bf16
              u16 hh = bf16rne(v);
              Qhi[(size_t)m * 1024 + col] = hh;
              Qlo[(size_t)m * 1024 + col] = bf16rne(v - bf16tof(hh));
            } else if (col < 2048) {     // K: hi bf16
              Khi[(size_t)m * 1024 + (col - 1024)] = bf16rne(v);
            } else {                     // V: transposed bf16
              Vt[(size_t)(col - 2048) * 4096 + m] = bf16rne(v);
            }
          } else {
            C[(size_t)m * ldc + col] = v;
          }
        }
      }
    }
  }
}

// ---------------------------------------------------------------------------
// MFMA flash attention. grid = B*H*(T/64) = 1024 blocks, 256 thr (4 waves).
// S via mfma(Kh, Qhi) + mfma(Kh, Qlo); Q read directly as split bf16.
// Epilogue writes out_pre split hi/lo bf16 (feeds Wo GEMM directly).
// ---------------------------------------------------------------------------
__global__ __launch_bounds__(256) void attn_fused_mfma(
    const u16* __restrict__ Qhi, const u16* __restrict__ Qlo,
    const u16* __restrict__ Khi, const u16* __restrict__ Vt,
    float* __restrict__ mrow, float* __restrict__ linv,
    u16* __restrict__ ophi, u16* __restrict__ oplo) {
  __shared__ u16 Kh_s[64][72];
  __shared__ u16 Vt_s[64][72];
  __shared__ u16 P_s[4][16][72];
  __shared__ float c_s[4][16];
  const int bi = blockIdx.x;
  const int qt = bi & 15, h = (bi >> 4) & 15, b = bi >> 8;
  const int tid = threadIdx.x;
  const int lane = tid & 63, w = tid >> 6;
  const int l15 = lane & 15, g = lane >> 4;
  const int q0 = qt * 64 + w * 16;
  const float scale = 0.125f;
  bf16x8 qh[2], ql[2];
  {
    size_t qoff = (size_t)(b * T_ + q0 + l15) * 1024 + h * DH_;
    qh[0] = *(const bf16x8*)&Qhi[qoff + 8 * g];
    qh[1] = *(const bf16x8*)&Qhi[qoff + 32 + 8 * g];
    ql[0] = *(const bf16x8*)&Qlo[qoff + 8 * g];
    ql[1] = *(const bf16x8*)&Qlo[qoff + 32 + 8 * g];
  }
  float m_run = -1e30f, l_run = 0.f;
  f32x4 acc_o[4];
#pragma unroll
  for (int nf = 0; nf < 4; nf++) {
    acc_o[nf][0] = 0.f; acc_o[nf][1] = 0.f; acc_o[nf][2] = 0.f; acc_o[nf][3] = 0.f;
  }

#pragma unroll 1
  for (int kt = 0; kt < 16; kt++) {
    {
      int r = tid >> 2, cs = (tid & 3) * 16;
      size_t krow = (size_t)(b * T_ + kt * 64 + r) * 1024 + h * DH_ + cs;
      *(uint4*)&Kh_s[r][cs]     = *(const uint4*)&Khi[krow];
      *(uint4*)&Kh_s[r][cs + 8] = *(const uint4*)&Khi[krow + 8];
      size_t vrow = (size_t)r * 4096 + b * T_ + kt * 64 + cs;
      *(uint4*)&Vt_s[r][cs]     = *(const uint4*)&Vt[vrow];
      *(uint4*)&Vt_s[r][cs + 8] = *(const uint4*)&Vt[vrow + 8];
    }
    __syncthreads();
    f32x4 accs[4];
#pragma unroll
    for (int mf = 0; mf < 4; mf++) {
      accs[mf][0] = 0.f; accs[mf][1] = 0.f; accs[mf][2] = 0.f; accs[mf][3] = 0.f;
    }
#pragma unroll
    for (int mf = 0; mf < 4; mf++) {
#pragma unroll
      for (int ks = 0; ks < 2; ks++) {
        bf16x8 kh = *(bf16x8*)&Kh_s[mf * 16 + l15][ks * 32 + 8 * g];
        accs[mf] = __builtin_amdgcn_mfma_f32_16x16x32_bf16(kh, qh[ks], accs[mf], 0, 0, 0);
        accs[mf] = __builtin_amdgcn_mfma_f32_16x16x32_bf16(kh, ql[ks], accs[mf], 0, 0, 0);
      }
    }
    float tm = -1e30f;
#pragma unroll
    for (int mf = 0; mf < 4; mf++)
#pragma unroll
      for (int r = 0; r < 4; r++) {
        accs[mf][r] *= scale;
        tm = fmaxf(tm, accs[mf][r]);
      }
    tm = fmaxf(tm, __shfl_xor(tm, 16));
    tm = fmaxf(tm, __shfl_xor(tm, 32));
    float m_new = fmaxf(m_run, tm);
    float crs = __expf(m_run - m_new);
    float ts = 0.f;
#pragma unroll
    for (int mf = 0; mf < 4; mf++) {
      float p0 = __expf(accs[mf][0] - m_new);
      float p1 = __expf(accs[mf][1] - m_new);
      float p2 = __expf(accs[mf][2] - m_new);
      float p3 = __expf(accs[mf][3] - m_new);
      ts += (p0 + p1) + (p2 + p3);
      u32 w0 = (u32)bf16rne(p0) | ((u32)bf16rne(p1) << 16);
      u32 w1 = (u32)bf16rne(p2) | ((u32)bf16rne(p3) << 16);
      *(uint2*)&P_s[w][l15][16 * mf + 4 * g] = make_uint2(w0, w1);
    }
    ts += __shfl_xor(ts, 16);
    ts += __shfl_xor(ts, 32);
    l_run = l_run * crs + ts;
    m_run = m_new;
    if (g == 0) c_s[w][l15] = crs;
    __syncthreads();
    float4 cc = *(float4*)&c_s[w][4 * g];
    float cca[4] = {cc.x, cc.y, cc.z, cc.w};
#pragma unroll
    for (int nf = 0; nf < 4; nf++)
#pragma unroll
      for (int r = 0; r < 4; r++) acc_o[nf][r] *= cca[r];
    bf16x8 pa[2];
    pa[0] = *(bf16x8*)&P_s[w][l15][8 * g];
    pa[1] = *(bf16x8*)&P_s[w][l15][32 + 8 * g];
#pragma unroll
    for (int nf = 0; nf < 4; nf++) {
#pragma unroll
      for (int ks = 0; ks < 2; ks++) {
        bf16x8 vb = *(bf16x8*)&Vt_s[nf * 16 + l15][ks * 32 + 8 * g];
        acc_o[nf] = __builtin_amdgcn_mfma_f32_16x16x32_bf16(pa[ks], vb, acc_o[nf], 0, 0, 0);
      }
    }
    __syncthreads();
  }
  float li = 1.0f / l_run;
  if (g == 0) {
    int idx = (b * H_ + h) * T_ + q0 + l15;
    mrow[idx] = m_run;
    linv[idx] = li;
    c_s[w][l15] = li;
  }
  __syncthreads();
  float4 lc = *(float4*)&c_s[w][4 * g];
  float lca[4] = {lc.x, lc.y, lc.z, lc.w};
#pragma unroll
  for (int nf = 0; nf < 4; nf++)
#pragma unroll
    for (int r = 0; r < 4; r++) {
      float v = acc_o[nf][r] * lca[r];
      u16 hh = bf16rne(v);
      u16 ll = bf16rne(v - bf16tof(hh));
      size_t idx = (size_t)(b * T_ + q0 + 4 * g + r) * D_ + h * DH_ + nf * 16 + l15;
      ophi[idx] = hh;
      oplo[idx] = ll;
    }
}

// ---------------------------------------------------------------------------
// MFMA attn_mean. grid = B*(T/64)*(T/64) = 1024 blocks. 1-pass S (Qhi only):
// dropped kh@ql ~3.8e-4 rms on scores, /4 after head-averaging.
// ---------------------------------------------------------------------------
__global__ __launch_bounds__(256) void attn_mean_mfma(
    const u16* __restrict__ Qhi, const u16* __restrict__ Khi,
    const float* __restrict__ mrow, const float* __restrict__ linv,
    float* __restrict__ am_out) {
  __shared__ u16 Kh_s[64][72];
  const int bi = blockIdx.x;
  const int kc = bi & 15, qt = (bi >> 4) & 15, b = bi >> 8;
  const int tid = threadIdx.x;
  const int lane = tid & 63, w = tid >> 6;
  const int l15 = lane & 15, g = lane >> 4;
  const int q0 = qt * 64 + w * 16, k0 = kc * 64;
  const float scale = 0.125f;
  float am[4][4] = {};
#pragma unroll 1
  for (int h = 0; h < H_; h++) {
    {
      int r = tid >> 2, cs = (tid & 3) * 16;
      size_t krow = (size_t)(b * T_ + k0 + r) * 1024 + h * DH_ + cs;
      *(uint4*)&Kh_s[r][cs]     = *(const uint4*)&Khi[krow];
      *(uint4*)&Kh_s[r][cs + 8] = *(const uint4*)&Khi[krow + 8];
    }
    __syncthreads();
    bf16x8 qh[2];
    {
      size_t qoff = (size_t)(b * T_ + q0 + l15) * 1024 + h * DH_;
      qh[0] = *(const bf16x8*)&Qhi[qoff + 8 * g];
      qh[1] = *(const bf16x8*)&Qhi[qoff + 32 + 8 * g];
    }
    f32x4 accs[4];
#pragma unroll
    for (int mf = 0; mf < 4; mf++) {
      accs[mf][0] = 0.f; accs[mf][1] = 0.f; accs[mf][2] = 0.f; accs[mf][3] = 0.f;
    }
#pragma unroll
    for (int mf = 0; mf < 4; mf++) {
#pragma unroll
      for (int ks = 0; ks < 2; ks++) {
        bf16x8 kh = *(bf16x8*)&Kh_s[mf * 16 + l15][ks * 32 + 8 * g];
        accs[mf] = __builtin_amdgcn_mfma_f32_16x16x32_bf16(kh, qh[ks], accs[mf], 0, 0, 0);
      }
    }
    const float mq = mrow[(b * H_ + h) * T_ + q0 + l15];
    const float li = linv[(b * H_ + h) * T_ + q0 + l15];
#pragma unroll
    for (int mf = 0; mf < 4; mf++)
#pragma unroll
      for (int r = 0; r < 4; r++)
        am[mf][r] += __expf(accs[mf][r] * scale - mq) * li;
    __syncthreads();
  }
  const float inv16 = 1.0f / 16.0f;
#pragma unroll
  for (int mf = 0; mf < 4; mf++) {
    float4 o;
    o.x = am[mf][0] * inv16; o.y = am[mf][1] * inv16;
    o.z = am[mf][2] * inv16; o.w = am[mf][3] * inv16;
    *(float4*)&am_out[(size_t)(b * T_ + q0 + l15) * T_ + k0 + 16 * mf + 4 * g] = o;
  }
}

// ---------------------------------------------------------------------------
extern "C" void kernel_launch(void* const* d_in, const int* in_sizes, int n_in,
                              void* d_out, int out_size, void* d_ws, size_t ws_size,
                              hipStream_t stream) {
  const float* x  = (const float*)d_in[0];
  const float* Wq = (const float*)d_in[1];
  const float* bq = (const float*)d_in[2];
  const float* Wk = (const float*)d_in[3];
  const float* bk = (const float*)d_in[4];
  const float* Wv = (const float*)d_in[5];
  const float* bv = (const float*)d_in[6];
  const float* Wo = (const float*)d_in[7];
  const float* bo = (const float*)d_in[8];

  float* out = (float*)d_out;                      // [B,T,D]
  float* am  = out + (size_t)B_ * T_ * D_;         // [B,T,T]

  char* w = (char*)d_ws;
  u16* Qhi   = (u16*)w; w += (size_t)4096 * 1024 * 2;
  u16* Qlo   = (u16*)w; w += (size_t)4096 * 1024 * 2;
  u16* Khi   = (u16*)w; w += (size_t)4096 * 1024 * 2;
  u16* Vt    = (u16*)w; w += (size_t)64 * 4096 * 2;
  u16* xhi   = (u16*)w; w += (size_t)4096 * 1024 * 2;  // x-split, then out_pre hi
  u16* xlo   = (u16*)w; w += (size_t)4096 * 1024 * 2;  // x-split, then out_pre lo
  u16* WcThi = (u16*)w; w += (size_t)NCAT * 1024 * 2;
  u16* WcTlo = (u16*)w; w += (size_t)NCAT * 1024 * 2;
  u16* WoThi = (u16*)w; w += (size_t)1024 * 1024 * 2;
  u16* WoTlo = (u16*)w; w += (size_t)1024 * 1024 * 2;
  float* mrow  = (float*)w; w += (size_t)B_ * H_ * T_ * 4;
  float* linvp = (float*)w; w += (size_t)B_ * H_ * T_ * 4;
  float* bcat  = (float*)w; w += (size_t)NCAT * 4;

  wprep<<<785, 256, 0, stream>>>(Wq, Wk, Wv, Wo, bq, bk, bv,
                                 WcThi, WcTlo, WoThi, WoTlo, bcat);
  rowconv<<<2048, 256, 0, stream>>>(x, xhi, xlo);

  // QKV GEMM -> Qhi/Qlo (split), Khi (bf16), Vt (bf16 transposed)
  mfma_gemm<128, true><<<dim3(32, 17), 256, 0, stream>>>(
      xhi, xlo, WcThi, WcTlo, bcat, nullptr, NCAT, 1024, 0,
      Qhi, Qlo, Khi, Vt);

  attn_fused_mfma<<<1024, 256, 0, stream>>>(Qhi, Qlo, Khi, Vt,
                                            mrow, linvp, xhi, xlo);
  attn_mean_mfma<<<1024, 256, 0, stream>>>(Qhi, Khi, mrow, linvp, am);

  mfma_gemm<64, false><<<dim3(64, 8), 256, 0, stream>>>(
      xhi, xlo, WoThi, WoTlo, bo, out, 1024, 1024, 1024,
      nullptr, nullptr, nullptr, nullptr);
}